// Round 10
// baseline (2581.670 us; speedup 1.0000x reference)
//
#include <hip/hip_runtime.h>
#include <cstddef>

#define LRATE 3e-4f

typedef short short8 __attribute__((ext_vector_type(8)));
typedef float f32x4 __attribute__((ext_vector_type(4)));
typedef __bf16 bf16x8 __attribute__((ext_vector_type(8)));

__device__ __forceinline__ unsigned short f2b(float f){
  unsigned u = __builtin_bit_cast(unsigned, f);
  unsigned r = (u + 0x7fffu + ((u>>16)&1u)) >> 16;
  return (unsigned short)r;
}
__device__ __forceinline__ float b2f(unsigned short s){
  unsigned u = ((unsigned)s)<<16;
  return __builtin_bit_cast(float, u);
}
__device__ __forceinline__ float gelu_f(float x){
  float u = 0.7978845608028654f*(x + 0.044715f*x*x*x);
  float t = tanhf(u);
  return 0.5f*x*(1.f+t);
}
__device__ __forceinline__ float gelu_df(float x){
  float x2 = x*x;
  float u = 0.7978845608028654f*(x + 0.044715f*x*x2);
  float t = tanhf(u);
  return 0.5f*(1.f+t) + 0.5f*x*(1.f-t*t)*0.7978845608028654f*(1.f+0.134145f*x2);
}
__device__ __forceinline__ void gll16(const void* g, void* l){
  __builtin_amdgcn_global_load_lds(
      (const __attribute__((address_space(1))) unsigned int*)(g),
      (__attribute__((address_space(3))) unsigned int*)(l), 16, 0, 0);
}
__device__ __forceinline__ bf16x8 frag_read(const short* base, int row, int h, int kg){
  int c = (h*4+kg) ^ (row&7);
  return __builtin_bit_cast(bf16x8, *(const short8*)((const char*)base + row*128 + c*16));
}
__device__ __forceinline__ void tr_write(short* base, int nrow, int k, unsigned short v){
  *(short*)((char*)base + nrow*128 + (((k>>3)^(nrow&7))<<4) + (k&7)*2) = (short)v;
}

// ============ TILE=128 NT bf16 MFMA GEMM, 2-phase pipelined (head fwd/bwd only) ============
template<int TILE, int LNA, int STATS>
__global__ __launch_bounds__(256) void k_nt(
    const unsigned short* __restrict__ Ag,
    const float* __restrict__ Af, const float* __restrict__ aS1, const float* __restrict__ aS2,
    const float* __restrict__ lng, const float* __restrict__ lnb,
    const unsigned short* __restrict__ Bg,
    const float* __restrict__ bias, const float* __restrict__ resid, const float* __restrict__ zsrc,
    float* __restrict__ outf, unsigned short* __restrict__ outb,
    float* __restrict__ oS1, float* __restrict__ oS2,
    int M, int N, int K, int k_iters, int gelu_b, int remap_c)
{
  constexpr int F = TILE/32;
  constexpr int CH = TILE/32;
  __shared__ __align__(16) short Asm[2*TILE*64];
  __shared__ __align__(16) short Bsm[2*TILE*64];
  int tid=threadIdx.x, lane=tid&63, w=tid>>6;
  int wr=w>>1, wc=w&1, r16=lane&15, kg=lane>>4;
  int bn=blockIdx.x*TILE, bm=blockIdx.y*TILE;
  int kbase = blockIdx.z*k_iters*64;
  f32x4 acc[F][F]={};

  int ids[CH], rows[CH];
  float mA[CH], rA[CH];
  #pragma unroll
  for(int q=0;q<CH;q++){ ids[q]=w*(TILE*2)+q*64+lane; rows[q]=ids[q]>>3; }
  if constexpr(LNA){
    #pragma unroll
    for(int q=0;q<CH;q++){
      float s1=aS1[bm+rows[q]], s2=aS2[bm+rows[q]];
      float mm=s1*(1.f/512.f);
      mA[q]=mm; rA[q]=rsqrtf(s2*(1.f/512.f)-mm*mm+1e-5f);
    }
  }

  auto STAGE=[&](int t,int buf){
    int k0 = kbase + t*64;
    short* Ad = Asm + buf*TILE*64;
    short* Bd = Bsm + buf*TILE*64;
    if constexpr(LNA==0){
      #pragma unroll
      for(int q=0;q<CH;q++){
        int gc=(ids[q]&7)^(rows[q]&7);
        gll16(Ag + (size_t)(bm+rows[q])*K + k0 + gc*8, (char*)Ad + ids[q]*16);
      }
    } else {
      #pragma unroll
      for(int q=0;q<CH;q++){
        int gc=(ids[q]&7)^(rows[q]&7);
        const float* src = Af + (size_t)(bm+rows[q])*K + k0 + gc*8;
        float4 v0=*(const float4*)src, v1=*(const float4*)(src+4);
        const float* gp=lng+k0+gc*8; const float* bp=lnb+k0+gc*8;
        float4 g0=*(const float4*)gp, g1=*(const float4*)(gp+4);
        float4 c0=*(const float4*)bp, c1=*(const float4*)(bp+4);
        float mm=mA[q], rr=rA[q];
        short8 o;
        o[0]=(short)f2b((v0.x-mm)*rr*g0.x+c0.x);
        o[1]=(short)f2b((v0.y-mm)*rr*g0.y+c0.y);
        o[2]=(short)f2b((v0.z-mm)*rr*g0.z+c0.z);
        o[3]=(short)f2b((v0.w-mm)*rr*g0.w+c0.w);
        o[4]=(short)f2b((v1.x-mm)*rr*g1.x+c1.x);
        o[5]=(short)f2b((v1.y-mm)*rr*g1.y+c1.y);
        o[6]=(short)f2b((v1.z-mm)*rr*g1.z+c1.z);
        o[7]=(short)f2b((v1.w-mm)*rr*g1.w+c1.w);
        *(short8*)((char*)Ad + ids[q]*16) = o;
      }
    }
    #pragma unroll
    for(int q=0;q<CH;q++){
      int gc=(ids[q]&7)^(rows[q]&7);
      gll16(Bg + (size_t)(bn+rows[q])*K + k0 + gc*8, (char*)Bd + ids[q]*16);
    }
  };

  STAGE(0,0);
  for(int t=0;t<k_iters;++t){
    int buf=t&1;
    STAGE(t+1<k_iters?t+1:t, buf^1);
    asm volatile("" ::: "memory");
    constexpr int VMC = LNA ? (TILE/32) : (TILE/16);
    if constexpr(VMC==2)      asm volatile("s_waitcnt vmcnt(2)" ::: "memory");
    else if constexpr(VMC==4) asm volatile("s_waitcnt vmcnt(4)" ::: "memory");
    else                      asm volatile("s_waitcnt vmcnt(8)" ::: "memory");
    __builtin_amdgcn_sched_barrier(0);
    __builtin_amdgcn_s_barrier();
    asm volatile("" ::: "memory");
    const char* Ab=(const char*)(Asm+buf*TILE*64);
    const char* Bb=(const char*)(Bsm+buf*TILE*64);
    #pragma unroll
    for(int h=0;h<2;h++){
      bf16x8 af[F], bfr[F];
      #pragma unroll
      for(int fa=0;fa<F;fa++){
        int row=wr*(TILE/2)+fa*16+r16;
        int c=(h*4+kg)^(row&7);
        af[fa]=__builtin_bit_cast(bf16x8, *(const short8*)(Ab + row*128 + c*16));
      }
      #pragma unroll
      for(int fb=0;fb<F;fb++){
        int row=wc*(TILE/2)+fb*16+r16;
        int c=(h*4+kg)^(row&7);
        bfr[fb]=__builtin_bit_cast(bf16x8, *(const short8*)(Bb + row*128 + c*16));
      }
      #pragma unroll
      for(int fa=0;fa<F;fa++)
        #pragma unroll
        for(int fb=0;fb<F;fb++)
          acc[fa][fb]=__builtin_amdgcn_mfma_f32_16x16x32_bf16(af[fa],bfr[fb],acc[fa][fb],0,0,0);
    }
    asm volatile("s_waitcnt lgkmcnt(0)" ::: "memory");
    __builtin_amdgcn_sched_barrier(0);
    __builtin_amdgcn_s_barrier();
    asm volatile("" ::: "memory");
  }
  asm volatile("s_waitcnt vmcnt(0)" ::: "memory");

  int rb = lane>>4;
  float st1[F][4]={}, st2[F][4]={};
  #pragma unroll
  for(int fa=0; fa<F; fa++){
    #pragma unroll
    for(int fb=0; fb<F; fb++){
      f32x4 av = acc[fa][fb];
      #pragma unroll
      for(int i=0;i<4;i++){
        int m = bm + wr*(TILE/2) + fa*16 + rb*4 + i;
        int n = bn + wc*(TILE/2) + fb*16 + r16;
        float v = av[i];
        if(bias) v += bias[n];
        if(resid) v += resid[(size_t)m*N + n];
        if(zsrc) v *= gelu_df(zsrc[(size_t)m*N + n]);
        if constexpr(STATS){ st1[fa][i] += v; st2[fa][i] += v*v; }
        int mo = (remap_c>=0)? ((m>>6)*256 + remap_c*64 + (m&63)) : m;
        if(outf) outf[(size_t)blockIdx.z*M*N + (size_t)mo*N + n] = v;
        if(outb) outb[(size_t)mo*N + n] = f2b(gelu_b ? gelu_f(v) : v);
      }
    }
  }
  if constexpr(STATS){
    #pragma unroll
    for(int fa=0; fa<F; fa++){
      #pragma unroll
      for(int i=0;i<4;i++){
        float s1 = st1[fa][i], s2 = st2[fa][i];
        #pragma unroll
        for(int msk=1; msk<16; msk<<=1){ s1 += __shfl_xor(s1,msk); s2 += __shfl_xor(s2,msk); }
        if(r16==0){
          int m = bm + wr*(TILE/2) + fa*16 + rb*4 + i;
          atomicAdd(&oS1[m], s1);
          atomicAdd(&oS2[m], s2);
        }
      }
    }
  }
}

// ============ TILE=32 NT GEMM, 8-slot rolling prefetch ============
// LNA=1: A = LayerNorm-fwd(Af) staged upfront. LNB=1: A = LayerNorm-bwd(dyf; x=Af; g=lng;
// stats; +adn) staged upfront; blockIdx.x==0 blocks also write oA (fp32) and oB2 (bf16).
template<int LNA, int STATS, int LNB>
__global__ __launch_bounds__(256) void k_nt32(
    const unsigned short* __restrict__ Ag,
    const float* __restrict__ Af, const float* __restrict__ aS1, const float* __restrict__ aS2,
    const float* __restrict__ lng, const float* __restrict__ lnb,
    const unsigned short* __restrict__ Bg,
    const float* __restrict__ bias, const float* __restrict__ resid, const float* __restrict__ zsrc,
    float* __restrict__ outf, unsigned short* __restrict__ outb,
    float* __restrict__ oS1, float* __restrict__ oS2,
    const float* __restrict__ dyf, const float* __restrict__ adn,
    float* __restrict__ oA, unsigned short* __restrict__ oB2,
    int M, int N, int K, int k_iters, int gelu_b)
{
  __shared__ __align__(16) short Asl[8*2048];
  __shared__ __align__(16) short Bsl[8*2048];
  int tid=threadIdx.x, lane=tid&63, w=tid>>6;
  int wr=w>>1, wc=w&1, r16=lane&15, kg=lane>>4;
  int bn=blockIdx.x*32, bm=blockIdx.y*32;
  int row=tid>>3, s8=tid&7, gc=s8^(row&7);
  f32x4 acc={0.f,0.f,0.f,0.f};

  auto ISSUE_A=[&](int t,int slot){
    gll16(Ag + (size_t)(bm+row)*K + t*64 + gc*8, (char*)Asl + slot*4096 + tid*16);
  };
  auto ISSUE_B=[&](int t,int slot){
    gll16(Bg + (size_t)(bn+row)*K + t*64 + gc*8, (char*)Bsl + slot*4096 + tid*16);
  };

  if constexpr(LNB){
    // B prefetch first (hide HBM under LN-bwd compute)
    #pragma unroll
    for(int s=0;s<6;s++) ISSUE_B(s, s);
    int grow = bm + row;
    float s1v=aS1[grow], s2v=aS2[grow];
    float m=s1v*(1.f/512.f);
    float r=rsqrtf(s2v*(1.f/512.f)-m*m+1e-5f);
    float sgh=0.f, sghx=0.f;
    for(int t=0;t<k_iters;t++){
      const float* dyp=dyf+(size_t)grow*512+t*64+gc*8;
      const float* xp =Af +(size_t)grow*512+t*64+gc*8;
      const float* gp =lng+t*64+gc*8;
      float4 a0=*(const float4*)dyp, a1=*(const float4*)(dyp+4);
      float4 x0=*(const float4*)xp,  x1=*(const float4*)(xp+4);
      float4 g0=*(const float4*)gp,  g1=*(const float4*)(gp+4);
      float dys[8]={a0.x,a0.y,a0.z,a0.w,a1.x,a1.y,a1.z,a1.w};
      float xs[8]={x0.x,x0.y,x0.z,x0.w,x1.x,x1.y,x1.z,x1.w};
      float gs[8]={g0.x,g0.y,g0.z,g0.w,g1.x,g1.y,g1.z,g1.w};
      #pragma unroll
      for(int j=0;j<8;j++){ float gh=dys[j]*gs[j]; float xh=(xs[j]-m)*r; sgh+=gh; sghx+=gh*xh; }
    }
    sgh +=__shfl_xor(sgh,1);  sgh +=__shfl_xor(sgh,2);  sgh +=__shfl_xor(sgh,4);
    sghx+=__shfl_xor(sghx,1); sghx+=__shfl_xor(sghx,2); sghx+=__shfl_xor(sghx,4);
    float mg=sgh*(1.f/512.f), mgx=sghx*(1.f/512.f);
    for(int t=0;t<k_iters;t++){
      const float* dyp=dyf+(size_t)grow*512+t*64+gc*8;
      const float* xp =Af +(size_t)grow*512+t*64+gc*8;
      const float* gp =lng+t*64+gc*8;
      const float* ap2=adn+(size_t)grow*512+t*64+gc*8;
      float4 a0=*(const float4*)dyp, a1=*(const float4*)(dyp+4);
      float4 x0=*(const float4*)xp,  x1=*(const float4*)(xp+4);
      float4 g0=*(const float4*)gp,  g1=*(const float4*)(gp+4);
      float4 d0=*(const float4*)ap2, d1=*(const float4*)(ap2+4);
      float dys[8]={a0.x,a0.y,a0.z,a0.w,a1.x,a1.y,a1.z,a1.w};
      float xs[8]={x0.x,x0.y,x0.z,x0.w,x1.x,x1.y,x1.z,x1.w};
      float gs[8]={g0.x,g0.y,g0.z,g0.w,g1.x,g1.y,g1.z,g1.w};
      float ads[8]={d0.x,d0.y,d0.z,d0.w,d1.x,d1.y,d1.z,d1.w};
      float dv[8];
      short8 o;
      #pragma unroll
      for(int j=0;j<8;j++){
        float gh=dys[j]*gs[j]; float xh=(xs[j]-m)*r;
        dv[j]=(gh-mg-xh*mgx)*r + ads[j];
        o[j]=(short)f2b(dv[j]);
      }
      *(short8*)((char*)Asl + t*4096 + tid*16) = o;
      if(blockIdx.x==0){
        float4 w0={dv[0],dv[1],dv[2],dv[3]}, w1={dv[4],dv[5],dv[6],dv[7]};
        *(float4*)(oA+(size_t)grow*512+t*64+gc*8) = w0;
        *(float4*)(oA+(size_t)grow*512+t*64+gc*8+4) = w1;
        *(short8*)(oB2+(size_t)grow*512+t*64+gc*8) = o;
      }
    }
    __syncthreads();
  }

  if constexpr(LNA){
    float mm, rr;
    { float a=aS1[bm+row], b=aS2[bm+row]; mm=a*(1.f/512.f); rr=rsqrtf(b*(1.f/512.f)-mm*mm+1e-5f); }
    for(int t=0;t<k_iters;t++){
      const float* src = Af + (size_t)(bm+row)*K + t*64 + gc*8;
      float4 v0=*(const float4*)src, v1=*(const float4*)(src+4);
      const float* gp=lng+t*64+gc*8; const float* bp=lnb+t*64+gc*8;
      float4 g0=*(const float4*)gp, g1=*(const float4*)(gp+4);
      float4 c0=*(const float4*)bp, c1=*(const float4*)(bp+4);
      short8 o;
      o[0]=(short)f2b((v0.x-mm)*rr*g0.x+c0.x);
      o[1]=(short)f2b((v0.y-mm)*rr*g0.y+c0.y);
      o[2]=(short)f2b((v0.z-mm)*rr*g0.z+c0.z);
      o[3]=(short)f2b((v0.w-mm)*rr*g0.w+c0.w);
      o[4]=(short)f2b((v1.x-mm)*rr*g1.x+c1.x);
      o[5]=(short)f2b((v1.y-mm)*rr*g1.y+c1.y);
      o[6]=(short)f2b((v1.z-mm)*rr*g1.z+c1.z);
      o[7]=(short)f2b((v1.w-mm)*rr*g1.w+c1.w);
      *(short8*)((char*)Asl + t*4096 + tid*16) = o;
    }
  }

  if constexpr(!LNB){
    #pragma unroll
    for(int s=0;s<6;s++){
      if constexpr(LNA==0) ISSUE_A(s, s);
      ISSUE_B(s, s);
    }
  }
  if constexpr(LNA){
    asm volatile("s_waitcnt lgkmcnt(0)" ::: "memory");
    __builtin_amdgcn_sched_barrier(0);
    __builtin_amdgcn_s_barrier();
  }

  constexpr int ARES = (LNA||LNB);   // A fully resident
  for(int t=0;t<k_iters;++t){
    int tt = (t+6<k_iters)? t+6 : k_iters-1;
    int slot=(t+6)&7;
    if constexpr(!ARES) ISSUE_A(tt, slot);
    ISSUE_B(tt, slot);
    if constexpr(!ARES) asm volatile("s_waitcnt vmcnt(12)" ::: "memory");
    else                asm volatile("s_waitcnt vmcnt(6)" ::: "memory");
    __builtin_amdgcn_sched_barrier(0);
    __builtin_amdgcn_s_barrier();
    __builtin_amdgcn_sched_barrier(0);
    const char* Ab = ARES ? (const char*)Asl + t*4096 : (const char*)Asl + (t&7)*4096;
    const char* Bb = (const char*)Bsl + (t&7)*4096;
    #pragma unroll
    for(int h=0;h<2;h++){
      int rowa=wr*16+r16, ca=(h*4+kg)^(rowa&7);
      bf16x8 a=__builtin_bit_cast(bf16x8, *(const short8*)(Ab + rowa*128 + ca*16));
      int rowb=wc*16+r16, cb=(h*4+kg)^(rowb&7);
      bf16x8 b=__builtin_bit_cast(bf16x8, *(const short8*)(Bb + rowb*128 + cb*16));
      acc=__builtin_amdgcn_mfma_f32_16x16x32_bf16(a,b,acc,0,0,0);
    }
    asm volatile("s_waitcnt lgkmcnt(0)" ::: "memory");
    __builtin_amdgcn_sched_barrier(0);
  }
  asm volatile("s_waitcnt vmcnt(0)" ::: "memory");

  int rb=lane>>4;
  float st1[4]={}, st2[4]={};
  #pragma unroll
  for(int i=0;i<4;i++){
    int m = bm + wr*16 + rb*4 + i;
    int n = bn + wc*16 + r16;
    float v = acc[i];
    if(bias) v += bias[n];
    if(resid) v += resid[(size_t)m*N + n];
    if(zsrc) v *= gelu_df(zsrc[(size_t)m*N + n]);
    if constexpr(STATS){ st1[i]=v; st2[i]=v*v; }
    if(outf) outf[(size_t)m*N + n] = v;
    if(outb) outb[(size_t)m*N + n] = f2b(gelu_b ? gelu_f(v) : v);
  }
  if constexpr(STATS){
    #pragma unroll
    for(int i=0;i<4;i++){
      float s1=st1[i], s2=st2[i];
      #pragma unroll
      for(int msk=1;msk<16;msk<<=1){ s1+=__shfl_xor(s1,msk); s2+=__shfl_xor(s2,msk); }
      if(r16==0){
        int m = bm + wr*16 + rb*4 + i;
        atomicAdd(&oS1[m], s1);
        atomicAdd(&oS2[m], s2);
      }
    }
  }
}

// ============ TN wgrad + SGD body ============
template<int LNA>
__device__ __forceinline__ void sgd_body(
    const unsigned short* __restrict__ Ag,
    const float* __restrict__ Af, const float* __restrict__ aS1, const float* __restrict__ aS2,
    const float* __restrict__ lng, const float* __restrict__ lnb,
    const unsigned short* __restrict__ Bg,
    float* __restrict__ Wf, unsigned short* __restrict__ Wb, unsigned short* __restrict__ Wt,
    float* __restrict__ bv, int M, int N, int bm, int bn,
    short* Asm, short* Bsm, short* Tsm)
{
  int tid = threadIdx.x;
  f32x4 acc00={},acc01={},acc10={},acc11={};
  int lane = tid&63, w = tid>>6, wr = w>>1, wc = w&1;
  int r16 = lane&15, kg = lane>>4;
  float gv[8], bvv[8];
  if constexpr(LNA){
    int ms=(tid&7)*8;
    #pragma unroll
    for(int j=0;j<8;j++){ gv[j]=lng[bm+ms+j]; bvv[j]=lnb[bm+ms+j]; }
  }
  float csum = 0.f;
  int docs = (bv && bm==0 && tid<64);
  for(int k0=0; k0<256; k0+=32){
    if constexpr(LNA==0){
      int kk = tid>>3, ms=(tid&7)*8;
      short8 v = *(const short8*)(Ag + (size_t)(k0+kk)*M + bm + ms);
      #pragma unroll
      for(int j=0;j<8;j++){ int row=ms+j; Asm[row*40 + (((kk>>3)^((row>>3)&3))<<3) + (kk&7)] = v[j]; }
    } else {
      int kk = tid>>3, ms=(tid&7)*8;
      int token = k0+kk;
      float s1=aS1[token], s2=aS2[token];
      float mm=s1*(1.f/512.f);
      float rr=rsqrtf(s2*(1.f/512.f)-mm*mm+1e-5f);
      const float* src = Af + (size_t)token*M + bm + ms;
      float4 v0=*(const float4*)src, v1=*(const float4*)(src+4);
      float vals[8]={v0.x,v0.y,v0.z,v0.w,v1.x,v1.y,v1.z,v1.w};
      #pragma unroll
      for(int j=0;j<8;j++){
        int row=ms+j;
        Asm[row*40 + (((kk>>3)^((row>>3)&3))<<3) + (kk&7)] = (short)f2b((vals[j]-mm)*rr*gv[j]+bvv[j]);
      }
    }
    { int kk = tid>>3, ns=(tid&7)*8;
      short8 v = *(const short8*)(Bg + (size_t)(k0+kk)*N + bn + ns);
      #pragma unroll
      for(int j=0;j<8;j++){ int row=ns+j; Bsm[row*40 + (((kk>>3)^((row>>3)&3))<<3) + (kk&7)] = v[j]; } }
    __syncthreads();
    if(docs){
      #pragma unroll
      for(int kk2=0;kk2<32;kk2++)
        csum += b2f((unsigned short)Bsm[tid*40 + (((kk2>>3)^((tid>>3)&3))<<3) + (kk2&7)]);
    }
    int ra0 = wr*32 + r16, ra1 = ra0+16, rb0 = wc*32 + r16, rb1 = rb0+16;
    bf16x8 a0 = __builtin_bit_cast(bf16x8, *(const short8*)(Asm + ra0*40 + ((kg ^ ((ra0>>3)&3))<<3)));
    bf16x8 a1 = __builtin_bit_cast(bf16x8, *(const short8*)(Asm + ra1*40 + ((kg ^ ((ra1>>3)&3))<<3)));
    bf16x8 b0 = __builtin_bit_cast(bf16x8, *(const short8*)(Bsm + rb0*40 + ((kg ^ ((rb0>>3)&3))<<3)));
    bf16x8 b1 = __builtin_bit_cast(bf16x8, *(const short8*)(Bsm + rb1*40 + ((kg ^ ((rb1>>3)&3))<<3)));
    acc00 = __builtin_amdgcn_mfma_f32_16x16x32_bf16(a0, b0, acc00, 0,0,0);
    acc01 = __builtin_amdgcn_mfma_f32_16x16x32_bf16(a0, b1, acc01, 0,0,0);
    acc10 = __builtin_amdgcn_mfma_f32_16x16x32_bf16(a1, b0, acc10, 0,0,0);
    acc11 = __builtin_amdgcn_mfma_f32_16x16x32_bf16(a1, b1, acc11, 0,0,0);
    __syncthreads();
  }
  if(docs) bv[bn+tid] -= LRATE*csum;
  int rb = lane>>4;
  #pragma unroll
  for(int ar=0;ar<2;ar++){
    #pragma unroll
    for(int bc=0;bc<2;bc++){
      f32x4 av = (ar==0) ? (bc==0?acc00:acc01) : (bc==0?acc10:acc11);
      #pragma unroll
      for(int i=0;i<4;i++){
        int lm = wr*32 + ar*16 + rb*4 + i;
        int ln = wc*32 + bc*16 + r16;
        size_t oi = (size_t)(bm+lm)*N + bn+ln;
        float wv = Wf[oi] - LRATE*av[i];
        Wf[oi] = wv;
        unsigned short ub = f2b(wv);
        Wb[oi] = ub;
        Tsm[ln*72 + lm] = (short)ub;
      }
    }
  }
  __syncthreads();
  #pragma unroll
  for(int q=0;q<2;q++){
    int id = tid*2+q;
    int ln = id>>3, ch = id&7;
    short8 vv = *(const short8*)(Tsm + ln*72 + ch*8);
    *(short8*)(Wt + (size_t)(bn+ln)*M + bm + ch*8) = vv;
  }
}

__global__ __launch_bounds__(256) void k_sgd_all(
    const unsigned short* __restrict__ z1gs, const unsigned short* __restrict__ dh2bB,
    const unsigned short* __restrict__ dz1bs, const float* __restrict__ h1s,
    const float* __restrict__ stats, int c,
    float* W1c, unsigned short* W1b, unsigned short* W1t, float* B1c,
    float* W2c, unsigned short* W2b, unsigned short* W2t, float* B2c,
    const float* __restrict__ ln2_g, const float* __restrict__ ln2_b)
{
  __shared__ __align__(16) short Asm[64*40], Bsm[64*40], Tsm[64*72];
  int gid = blockIdx.x;
  int i = gid>>9, r = gid&511;
  if(r<256){
    int bn=(r&7)*64, bm=(r>>3)*64;
    sgd_body<0>(z1gs+(size_t)i*524288, nullptr,nullptr,nullptr,nullptr,nullptr,
        dh2bB+(size_t)i*131072,
        W2c+(size_t)i*1048576, W2b+(size_t)i*1048576, W2t+(size_t)i*1048576, B2c+i*512,
        2048, 512, bm, bn, Asm,Bsm,Tsm);
  } else {
    int r2=r-256;
    int bn=(r2&31)*64, bm=(r2>>5)*64;
    const float* S1 = stats + ((size_t)(c*9+5+i)*2)*256;
    sgd_body<1>(nullptr, h1s+(size_t)i*131072, S1, S1+256, ln2_g+i*512, ln2_b+i*512,
        dz1bs+(size_t)i*524288,
        W1c+(size_t)i*1048576, W1b+(size_t)i*1048576, W1t+(size_t)i*1048576, B1c+i*2048,
        512, 2048, bm, bn, Asm,Bsm,Tsm);
  }
}

// ============ transpose-convert ============
__global__ __launch_bounds__(256) void k_cvt_t(const float* __restrict__ src,
    unsigned short* __restrict__ dstT, unsigned short* __restrict__ dstO, float* __restrict__ dstF,
    int R, int C)
{
  __shared__ __align__(16) short T[64*72];
  size_t zoff = (size_t)blockIdx.z * R * C;
  int c0 = blockIdx.x*64, r0 = blockIdx.y*64;
  int tid = threadIdx.x;
  #pragma unroll
  for(int q=0;q<16;q++){
    int e = tid + q*256;
    int r = e>>6, cc = e&63;
    float v = src[zoff + (size_t)(r0+r)*C + c0+cc];
    unsigned short bvu = f2b(v);
    T[cc*72 + r] = (short)bvu;
    if(dstO) dstO[zoff + (size_t)(r0+r)*C + c0+cc] = bvu;
    if(dstF) dstF[zoff + (size_t)(r0+r)*C + c0+cc] = v;
  }
  __syncthreads();
  #pragma unroll
  for(int q=0;q<2;q++){
    int id = tid*2+q;
    int cc = id>>3, ch = id&7;
    short8 vv = *(const short8*)(T + cc*72 + ch*8);
    *(short8*)(dstT + zoff + (size_t)(c0+cc)*R + r0 + ch*8) = vv;
  }
}

// ============ setup ============
__global__ __launch_bounds__(256) void k_setup(float* stats, float* B1c, const float* b1,
    float* B2c, const float* b2)
{
  int i = blockIdx.x*256 + threadIdx.x;
  if(i < 18432) stats[i] = 0.f;
  if(i < 8192)  B1c[i] = b1[i];
  if(i < 2048)  B2c[i] = b2[i];
}

// ============ embed + pos (+ LN stats) ============
__global__ __launch_bounds__(256) void k_embed(const int* __restrict__ x, const float* __restrict__ emb,
    const float* __restrict__ pos, float* __restrict__ h, float* __restrict__ S1, float* __restrict__ S2, int chunk)
{
  int n = blockIdx.x, tid = threadIdx.x;
  int b = n>>6, t = n&63;
  int tok = x[b*257 + chunk*64 + t];
  size_t b0 = (size_t)n*512 + tid;
  float v0 = emb[(size_t)tok*512 + tid]       + pos[t*512 + tid];
  float v1 = emb[(size_t)tok*512 + tid + 256] + pos[t*512 + tid + 256];
  h[b0] = v0; h[b0+256] = v1;
  __shared__ float r1[256], r2[256];
  r1[tid] = v0+v1; r2[tid] = v0*v0+v1*v1;
  __syncthreads();
  for(int o=128;o;o>>=1){ if(tid<o){ r1[tid]+=r1[tid+o]; r2[tid]+=r2[tid+o]; } __syncthreads(); }
  if(tid==0){ S1[n]=r1[0]; S2[n]=r2[0]; }
}

// ============ LayerNorm bwd (lnf only; wave-shuffle reductions; nz>0 sums split-K parts) ============
__global__ __launch_bounds__(256) void k_ln_bwd(const float* __restrict__ dy, const float* __restrict__ dp, int nz,
    const float* __restrict__ x, const float* __restrict__ g,
    const float* __restrict__ S1v, const float* __restrict__ S2v,
    const float* __restrict__ addin, float* __restrict__ dx, unsigned short* __restrict__ dxb)
{
  int n = blockIdx.x, tid = threadIdx.x;
  int lane = tid&63, w4 = tid>>6;
  float s1 = S1v[n], s2 = S2v[n];
  float m = s1*(1.f/512.f);
  float r = rsqrtf(s2*(1.f/512.f) - m*m + 1e-5f);
  size_t b0 = (size_t)n*512 + tid;
  float dy0, dy1;
  if(nz){
    dy0=0.f; dy1=0.f;
    for(int z=0;z<nz;z++){ dy0 += dp[(size_t)z*131072 + b0]; dy1 += dp[(size_t)z*131072 + b0 + 256]; }
  } else { dy0 = dy[b0]; dy1 = dy[b0+256]; }
  float x0 = x[b0], x1 = x[b0+256];
  float xh0 = (x0-m)*r, xh1 = (x1-m)*r;
  float gh0 = dy0*g[tid], gh1 = dy1*g[tid+256];
  float a1 = gh0+gh1, a2 = gh0*xh0 + gh1*xh1;
  #pragma unroll
  for(int off=32;off;off>>=1){ a1 += __shfl_xor(a1,off); a2 += __shfl_xor(a2,off); }
  __shared__ float rw[8];
  if(lane==0){ rw[w4]=a1; rw[4+w4]=a2; }
  __syncthreads();
  float mg  = (rw[0]+rw[1]+rw[2]+rw[3])*(1.f/512.f);
  float mgx = (rw[4]+rw[5]+rw[6]+rw[7])*(1.f/512.f);
  float d0 = (gh0 - mg - xh0*mgx)*r;
  float d1 = (gh1 - mg - xh1*mgx)*r;
  if(addin){ d0 += addin[b0]; d1 += addin[b0+256]; }
  dx[b0] = d0; dx[b0+256] = d1;
  dxb[b0] = f2b(d0); dxb[b0+256] = f2b(d1);
}

// ============ fused qkv GEMM (LN1 on-the-fly) + attention forward — 512 threads ============
__global__ __launch_bounds__(512) void k_qkv_attn(
    const float* __restrict__ h0, const float* __restrict__ S1, const float* __restrict__ S2,
    const float* __restrict__ lng, const float* __restrict__ lnb,
    const unsigned short* __restrict__ wT, const float* __restrict__ bias,
    unsigned short* __restrict__ qkB, unsigned short* __restrict__ obuf, unsigned short* __restrict__ ap)
{
  __shared__ __align__(16) short Afull[32768];
  __shared__ __align__(16) short Bsl[3*12288];
  short* Qs  = Bsl;
  short* Ks2 = Bsl + 4096;
  short* Vt  = Bsl + 8192;
  short* Pb  = Afull;
  float* Sf  = (float*)(Afull + 8192);
  int hh=blockIdx.x, bb=blockIdx.y;
  int tid=threadIdx.x, lane=tid&63, w=tid>>6;
  int r16=lane&15, kg=lane>>4, rb=lane>>4;

  {
    int arow=tid>>3, as8=tid&7, agc=as8^(arow&7);
    float mm,rr;
    { float a=S1[bb*64+arow], b2=S2[bb*64+arow]; mm=a*(1.f/512.f); rr=rsqrtf(b2*(1.f/512.f)-mm*mm+1e-5f); }
    for(int s=0;s<8;s++){
      const float* src = h0 + (size_t)(bb*64+arow)*512 + s*64 + agc*8;
      float4 v0=*(const float4*)src, v1=*(const float4*)(src+4);
      const float* gp=lng+s*64+agc*8; const float* bp=lnb+s*64+agc*8;
      float4 g0=*(const float4*)gp, g1=*(const float4*)(gp+4);
      float4 c0=*(const float4*)bp, c1=*(const float4*)(bp+4);
      short8 o;
      o[0]=(short)f2b((v0.x-mm)*rr*g0.x+c0.x);
      o[1]=(short)f2b((v0.y-mm)*rr*g0.y+c0.y);
      o[2]=(short)f2b((v0.z-mm)*rr*g0.z+c0.z);
      o[3]=(short)f2b((v0.w-mm)*rr*g0.w+c0.w);
      o[4]=(short)f2b((v1.x-mm)*rr*g1.x+c1.x);
      o[5]=(short)f2b((v1.y-mm)*rr*g1.y+c1.y);
      o[6]=(short)f2b((v1.z-mm)*rr*g1.z+c1.z);
      o[7]=(short)f2b((v1.w-mm)*rr*g1.w+c1.w);
      *(short8*)((char*)(Afull) + s*8192 + tid*16) = o;
    }
  }
  __syncthreads();

  auto STB=[&](int t,int slot){
    #pragma unroll
    for(int q=0;q<3;q++){
      int cid=q*512+tid, brow=cid>>3, s8=cid&7, gc=s8^(brow&7);
      int p=brow>>6, cin=brow&63;
      gll16(wT + (size_t)(p*512+hh*64+cin)*512 + t*64 + gc*8, (char*)Bsl + slot*24576 + cid*16);
    }
  };
  STB(0,0); STB(1,1);
  int wr=w>>2, wc=w&3;
  f32x4 acc[2][3]={};
  for(int t=0;t<8;t++){
    int tt=(t+2<8)? t+2 : 7;
    STB(tt,(t+2)%3);
    asm volatile("s_waitcnt vmcnt(6)" ::: "memory");
    __builtin_amdgcn_sched_barrier(0);
    __builtin_amdgcn_s_barrier();
    __builtin_amdgcn_sched_barrier(0);
    const char* Ab=(const char*)Afull + t*8192;
    const char* Bb=(const char*)Bsl + (t%3)*24576;
    #pragma unroll
    for(int h=0;h<2;h++){
      bf16x8 af[2], bfr[3];
      #pragma unroll
      for(int fa=0;fa<2;fa++){
        int rowa=wr*32+fa*16+r16, ca=(h*4+kg)^(rowa&7);
        af[fa]=__builtin_bit_cast(bf16x8, *(const short8*)(Ab + rowa*128 + ca*16));
      }
      #pragma unroll
      for(int fb=0;fb<3;fb++){
        int rowb=wc*48+fb*16+r16, cb=(h*4+kg)^(rowb&7);
        bfr[fb]=__builtin_bit_cast(bf16x8, *(const short8*)(Bb + rowb*128 + cb*16));
      }
      #pragma unroll
      for(int fa=0;fa<2;fa++)
        #pragma unroll
        for(int fb=0;fb<3;fb++)
          acc[fa][fb]=__builtin_amdgcn_mfma_f32_16x16x32_bf16(af[fa],bfr[fb],acc[fa][fb],0,0,0);
    }
    asm volatile("s_waitcnt lgkmcnt(0)" ::: "memory");
    __builtin_amdgcn_sched_barrier(0);
    __builtin_amdgcn_s_barrier();
    __builtin_amdgcn_sched_barrier(0);
  }
  asm volatile("s_waitcnt vmcnt(0)" ::: "memory");
  __syncthreads();

  #pragma unroll
  for(int fa=0;fa<2;fa++)
    #pragma unroll
    for(int fb=0;fb<3;fb++)
      #pragma unroll
      for(int i=0;i<4;i++){
        int row=wr*32+fa*16+rb*4+i;
        int band=wc*3+fb;
        int p=band>>2, cin=(band&3)*16+r16;
        float v = acc[fa][fb][i] + bias[p*512 + hh*64 + cin];
        unsigned short bv16 = f2b(v);
        qkB[(size_t)(bb*64+row)*1536 + p*512 + hh*64 + cin] = bv16;
        if(p==0)      tr_write(Qs,  row, cin, bv16);
        else if(p==1) tr_write(Ks2, row, cin, bv16);
        else          tr_write(Vt,  cin, row, bv16);
      }
  __syncthreads();

  int wr2=w>>2, wc2=w&3;
  f32x4 sa[2]={};
  #pragma unroll
  for(int h=0;h<2;h++){
    bf16x8 bfr = frag_read(Ks2, wc2*16+r16, h, kg);
    #pragma unroll
    for(int fa=0;fa<2;fa++){
      bf16x8 af = frag_read(Qs, wr2*32+fa*16+r16, h, kg);
      sa[fa]=__builtin_amdgcn_mfma_f32_16x16x32_bf16(af,bfr,sa[fa],0,0,0);
    }
  }
  #pragma unroll
  for(int fa=0;fa<2;fa++)
    #pragma unroll
    for(int i=0;i<4;i++){
      int row=wr2*32+fa*16+rb*4+i, col=wc2*16+r16;
      Sf[row*68+col] = (col<=row) ? sa[fa][i]*0.125f : -1e9f;
    }
  __syncthreads();

  {
    int srow=tid>>3, seg8=tid&7;
    float vals[8]; float mx=-3.4e38f;
    #pragma unroll
    for(int k2=0;k2<8;k2++){ vals[k2]=Sf[srow*68+seg8*8+k2]; mx=fmaxf(mx,vals[k2]); }
    mx=fmaxf(mx,__shfl_xor(mx,1)); mx=fmaxf(mx,__shfl_xor(mx,2)); mx=fmaxf(mx,__shfl_xor(mx,4));
    float sm=0;
    #pragma unroll
    for(int k2=0;k2<8;k2++){ vals[k2]=expf(vals[k2]-mx); sm+=vals[k2]; }
    sm+=__shfl_xor(sm,1); sm+=__shfl_xor(sm,2); sm+=__shfl_xor(sm,4);
    float inv=1.f/sm;
    short8 p0;
    #pragma unroll
    for(int k2=0;k2<8;k2++) p0[k2]=(short)f2b(vals[k2]*inv);
    __syncthreads();
    *(short8*)((char*)Pb + srow*128 + (((seg8)^(srow&7))<<4)) = p0;
    *(short8*)(ap + ((size_t)(bb*8+hh)*64 + srow)*64 + seg8*8) = p0;
  }
  __syncthreads();

  f32x4 oa[2]={};
  #pragma unroll
  for(int h=0;h<2;h++){
    bf16x8 bfr = frag_read(Vt, wc2*16+r16, h, kg);
    #pragma unroll
    for(int fa=0;fa<2;fa++){
      bf16x8 af = frag_read(Pb, wr2*32+fa*16+r16, h, kg);
      oa[fa]=__builtin_amdgcn_mfma_f32_16x16x32_bf16(af,bfr,oa[fa],0,0,0);
    }
  }
  #pragma unroll
  for(int fa=0;fa<2;fa++)
    #pragma unroll
    for(int i=0;i<4;i++){
      int row=wr2*32+fa*16+rb*4+i, col=wc2*16+r16;
      obuf[(size_t)(bb*64+row)*512 + hh*64 + col] = f2b(oa[fa][i]);
    }
}

// ============ fused LN2-bwd + do-GEMM + attention backward — 512 threads ============
// Computes dh1 = addin + LN2bwd(dxn) in-kernel (A operand, bit-identical to the old
// standalone ln_bwd); hh==0 blocks write dhB fp32. Then dO-GEMM + attn bwd.
__global__ __launch_bounds__(512) void k_do_attn(
    const float* __restrict__ dxn, const float* __restrict__ h1,
    const float* __restrict__ g2, const float* __restrict__ S1, const float* __restrict__ S2,
    const float* __restrict__ addin, float* __restrict__ dhB,
    const unsigned short* __restrict__ projwB,
    const unsigned short* __restrict__ qkvB, const unsigned short* __restrict__ ap,
    unsigned short* __restrict__ dqkv)
{
  __shared__ __align__(16) short Afull[32768];   // 64KB; post-GEMM aliased to dOs..dsT
  __shared__ __align__(16) short Bsl2[4*4096];   // 32KB; post-GEMM aliased to Pacc
  __shared__ __align__(16) short Vs[4096];
  __shared__ float rsum[64][2];
  short* dOs = Afull;
  short* Kt  = Afull + 4096;
  short* Qt  = Afull + 8192;
  short* dOt = Afull + 12288;
  short* Pt  = Afull + 16384;
  short* dsN = Afull + 20480;
  short* dsT = Afull + 24576;
  float* Pacc = (float*)Bsl2;
  int hh=blockIdx.x, bb=blockIdx.y;
  int tid=threadIdx.x, lane=tid&63, w=tid>>6;
  int wg=w>>2, wl=w&3;
  int wr=wl>>1, wc=wl&1, r16=lane&15, kg=lane>>4, rb=lane>>4;
  const unsigned short* qbase = qkvB + (size_t)bb*64*1536 + hh*64;
  const unsigned short* abase = ap + (size_t)(bb*8+hh)*64*64;

  // early: V -> LDS; K,Q,P -> regs (scattered after GEMM when Afull is free)
  int row8=tid>>3, c8=tid&7, gc8=c8^(row8&7);
  gll16(qbase + 1024 + (size_t)row8*1536 + gc8*8, (char*)Vs + tid*16);
  short8 kreg=*(const short8*)(qbase+512+(size_t)row8*1536+c8*8);
  short8 qreg=*(const short8*)(qbase+(size_t)row8*1536+c8*8);
  short8 preg=*(const short8*)(abase+(size_t)row8*64+c8*8);

  // B prefetch (group-split K: group wg owns segs wg*4..+3, 2 dbuf slots)
  const unsigned short* Bg = projwB + (size_t)(hh*64)*512;
  auto STB=[&](int t,int buf){
    #pragma unroll
    for(int q=0;q<2;q++){
      int id=wl*128+q*64+lane, brow=id>>3, bgc=(id&7)^(brow&7);
      gll16(Bg + (size_t)brow*512 + (wg*4+t)*64 + bgc*8, (char*)Bsl2 + (wg*2+buf)*8192 + id*16);
    }
  };
  STB(0,0);

  // ---- fused LN2-bwd -> Afull (GEMM A operand) + dhB global (hh==0) ----
  {
    int grow = bb*64 + row8;
    float s1v=S1[grow], s2v=S2[grow];
    float m=s1v*(1.f/512.f);
    float r=rsqrtf(s2v*(1.f/512.f)-m*m+1e-5f);
    float sgh=0.f, sghx=0.f;
    #pragma unroll
    for(int t=0;t<8;t++){
      const float* dyp = dxn + (size_t)grow*512 + t*64 + gc8*8;
      const float* xp  = h1  + (size_t)grow*512 + t*64 + gc8*8;
      const float* gp  = g2  + t*64 + gc8*8;
      float4 a0=*(const float4*)dyp, a1=*(const float4*)(dyp+4);
      float4 x0=*(const float4*)xp,  x1=*(const float4*)(xp+4);
      float4 g0=*(const float4*)gp,  g1=*(const float4*)(gp+4);
      float dys[8]={a0.x,a0.y,a0.z,a0.w,a1.x,a1.y,a1.z,a1.w};
      float xs[8]={x0.x,x0.y,x0.z,x0.w,x1.x,x1.y,x1.z,x1.w};
      float gs[8]={g0.x,g0.y,g0.z,g0.w,g1.x,g1.y,g1.z,g1.w};
      #pragma unroll
      for(int j=0;j<8;j++){ float gh=dys[j]*gs[j]; float xh=(xs[j]-m)*r; sgh+=gh; sghx+=gh*xh; }
    }
    sgh +=__shfl_xor(sgh,1);  sgh +=__shfl_xor(sgh,2);  sgh +=__shfl_xor(sgh,4);
    sghx+=__shfl_xor(sghx,1); sghx+=__shfl_xor(sghx,2); sghx+=__shfl_xor(sghx,4);
    float mg=sgh*(1.f/512.f), mgx=sghx*(1.f/512.f);
    #pragma unroll
    for(int t=0;t<8;t++){
      const float* dyp = dxn + (size_t)grow*512 + t*64 + gc8*8;
      const float* xp  = h1  + (size_t)grow*512 + t*64 + gc8*8;
      const float* gp  = g2  + t*64 + gc8*8;
      const float* ap2 = addin + (size_t)grow*512 + t*64 + gc8*8;
      float4 a0=*(const float4*)dyp, a1=*(const float4*)(dyp+4);
      float4 x0=*(const float4*)xp,  x1=*(const float4*)(xp+4);
      float4 g0=*(const float4*)gp,  g1=*(const float4*)(gp+4);
      float4 d0=*(const float4*)ap2, d1=*(const float4*)(ap2+4);
      float dys[8]={a0.x,a0.y,a0.z,a0.w,a1.x,a1.y,a1.z,a1.w};
      float xs[8]={x0.x,x0.y,x0.z,x0.w,x1.x,x1.y,x1.z,x1.w};
      float gs[8]={g0.x,g0.y,g0.z,g0.w,g1.x,g1.y,g1.z,g1.w};
      float ads[8]={d0.x,d0.y,d0.z,d0.w,d1.x,d1.y,d1.z,d1.w};
      float dv[8];
      short8 o;
      #pragma unroll
      for(int j=0;j<8;j++){
        float gh=dys[j]*gs[j]; float xh=(xs[j]-m)*r;
        dv[j]=(gh-mg-xh*mgx)*r + ads[j];
        o[j]=(short)f2b(dv[j]);
      }
      *(short8*)((char*)Afull + t*8192 + tid*16) = o;
      if(hh==0){
        float4 w0={dv[0],dv[1],dv[2],dv[3]}, w1={dv[4],dv[5],dv[6],dv[7]};
        *(float4*)(dhB + (size_t)grow*512 + t*64 + gc8*8) = w0;
        *(float4*)(dhB + (size_t)grow*512 + t*64 + gc8*8 + 4) = w1;
      }
    }
  }
  __syncthreads();

  // ---- dO GEMM: group wg handles K segs wg*4..+3 ----
  f32x4 acc[2][2]={};
  for(int t=0;t<4;t++){
    int buf=t&1;
    STB(t+1<4?t+1:t, buf^1);
    asm volatile("s_waitcnt vmcnt(2)" ::: "memory");
    __builtin_amdgcn_sched_barrier(0);
    __builtin_amdgcn_s_barrier();
    __builtin_amdgcn_sched_barrier(0);
    const char* Ab=(const char*)Afull + (wg*4+t)*8192;
    const char* Bb=(const char*)Bsl2 + (wg*2+buf)*8192;
    #pragma unroll
    for(int h=0;h<2;h++){
      bf16x8 af[2], bfr[2];
      #pragma unroll
      for(int f=0;f<2;f++){
        int rowa=wr*32+f*16+r16, ca=(h*4+kg)^(rowa&7);
        af[f]=__builtin_bit_cast(bf16x8, *(const short8*)(Ab + rowa*128 + ca*16));
        int rowb=wc*32+f*16+r16, cb=(h*4+kg)^(rowb&7);
        bfr[f]=__builtin_bit_cast(bf16x8, *(const short8*)(Bb + rowb*128 + cb*16));
      }
      #pragma unroll
      for(int fa=0;fa<2;fa++)
        #pragma unroll
        for(int fb=0;fb<2;fb++)
          acc[fa][fb]=__builtin_amdgcn_mfma_f32_16x16x32_bf16(af[fa],bfr[fb],acc[fa][fb],0,0,0);
    }
    asm volatile("s_waitcnt lgkmcnt(0)" ::: "memory");
    __builtin_amdgcn_sched_barrier(0);
    __builtin_amdgcn_s_barrier();
    __builtin_amdgcn_sched_barrier(0);
  }
  asm volatile("s_waitcnt vmcnt(0)" ::: "memory");
  __syncthreads();

  // combine partials (Pacc aliases Bsl2) + scatter K/Q/P (Afull now free)
  if(wg==1){
    #pragma unroll
    for(int fa=0;fa<2;fa++)
      #pragma unroll
      for(int fb=0;fb<2;fb++)
        #pragma unroll
        for(int i=0;i<4;i++){
          int row=wr*32+fa*16+rb*4+i, col=wc*32+fb*16+r16;
          Pacc[row*64+col]=acc[fa][fb][i];
        }
  }
  #pragma unroll
  for(int j=0;j<8;j++){
    int col=c8*8+j;
    tr_write(Kt, col, row8, (unsigned short)kreg[j]);
    tr_write(Qt, col, row8, (unsigned short)qreg[j]);
    tr_write(Pt, col, row8, (unsigned short)preg[j]);
  }
  __syncthreads();
  if(wg==0){
    #pragma unroll
    for(int fa=0;fa<2;fa++)
      #pragma unroll
      for(int fb=0;fb<2;fb++)
        #pragma unroll
        for(int i=0;i<4;i++){
          int row=wr*32+fa*16+rb*4+i, col=wc*32+fb*16+r16;
          unsigned short db = f2b(acc[fa][fb][i] + Pacc[row*64+col]);
          tr_write(dOs, row, col, db);
          tr_write(dOt, col, row, db);
        }
  }
  __syncthreads();

  // group0: dA = dO V^T + rowsum ;  group1: dv = P^T dO
  f32x4 da[2][2]={};
  float pv[2][2][4];
  if(wg==0){
    #pragma unroll
    for(int h=0;h<2;h++){
      bf16x8 af[2], bfr[2];
      #pragma unroll
      for(int f=0;f<2;f++){ af[f]=frag_read(dOs, wr*32+f*16+r16, h, kg); bfr[f]=frag_read(Vs, wc*32+f*16+r16, h, kg); }
      #pragma unroll
      for(int fa=0;fa<2;fa++)
        #pragma unroll
        for(int fb=0;fb<2;fb++)
          da[fa][fb]=__builtin_amdgcn_mfma_f32_16x16x32_bf16(af[fa],bfr[fb],da[fa][fb],0,0,0);
    }
    float part[2][4]={};
    #pragma unroll
    for(int fa=0;fa<2;fa++)
      #pragma unroll
      for(int i=0;i<4;i++){
        #pragma unroll
        for(int fb=0;fb<2;fb++){
          int row=wr*32+fa*16+rb*4+i, col=wc*32+fb*16+r16;
          float p = b2f(*(const unsigned short*)((const char*)Pt + col*128 + (((row>>3)^(col&7))<<4) + (row&7)*2));
          pv[fa][fb][i]=p;
          part[fa][i] += p*da[fa][fb][i];
        }
        float s=part[fa][i];
        #pragma unroll
        for(int msk=1;msk<16;msk<<=1) s += __shfl_xor(s,msk);
        if(r16==0) rsum[wr*32+fa*16+rb*4+i][wc]=s;
      }
  } else {
    f32x4 dvv[2][2]={};
    #pragma unroll
    for(int h=0;h<2;h++){
      bf16x8 af[2], bfr[2];
      #pragma unroll
      for(int f=0;f<2;f++){ af[f]=frag_read(Pt, wr*32+f*16+r16, h, kg); bfr[f]=frag_read(dOt, wc*32+f*16+r16, h, kg); }
      #pragma unroll
      for(int fa=0;fa<2;fa++)
        #pragma unroll
        for(int fb=0;fb<2;fb++)
          dvv[fa][fb]=__builtin_amdgcn_mfma_f32_16x16x32_bf16(af[fa],bfr[fb],dvv[fa][fb],0,0,0);
    }
    #pragma unroll
    for(int fa=0;fa<2;fa++)
      #pragma unroll
      for(int fb=0;fb<2;fb++)
        #pragma unroll
        for(int i=0;i<4;i++){
          int row=wr*32+fa*16+rb*4+i, col=wc*32+fb*16+r16;
          dqkv[(size_t)(bb*64+row)*1536 + hh*64 + 1024 + col] = f2b(dvv[fa][fb][i]);
        }
  }
  __syncthreads();

  if(wg==0){
    #pragma unroll
    for(int fa=0;fa<2;fa++)
      #pragma unroll
      for(int fb=0;fb<2;fb++)
        #pragma unroll
        for(int i=0;i<4;i++){
          int row=wr*32+fa*16+rb*4+i, col=wc*32+fb*16+r16;
          float rt = rsum[row][0]+rsum[row][1];
          float ds = pv[fa][fb][i]*(da[fa][fb][i]-rt)*0.125f;
          unsigned short db = f2b(ds);
          tr_write(dsN, row, col, db);
          tr_write(dsT, col, row, db);
        }
  }
  __syncthreads();

  {
    const short* Am = wg ? dsT : dsN;
    const short* Bm = wg ? Qt  : Kt;
    int ofs = wg ? 512 : 0;
    f32x4 a2[2][2]={};
    #pragma unroll
    for(int h=0;h<2;h++){
      bf16x8 af[2], bfr[2];
      #pragma unroll
      for(int f=0;f<2;f++){ af[f]=frag_read(Am, wr*32+f*16+r16, h, kg); bfr[f]=frag_read(Bm, wc*32+f*16+r16, h, kg); }
      #pragma unroll
      for(int fa=0;fa<2;fa++)
        #pragma unroll
        for(int fb=0;fb<2;fb++)
          a2[fa][fb]=__builtin_amdgcn_mfma_f32_16x16x32_bf16(af[fa],bfr[fb],a2[fa][fb],0,0,0);
    }
    #pragma unroll
    for(int fa=0;fa<2;fa++)
      #pragma unroll
      for(int fb=0;fb<2;fb++)
        #pragma unroll
        for(int i=0;i<4;i++){
          int row=wr*32+fa*16+rb*4+i, col=wc*32+fb*16+r16;
          dqkv[(size_t)(bb*64+row)*1536 + hh*64 + ofs + col] = f2b(a2[fa][fb][i]);
        }
  }
}

// ============ fused CE stats + dlogits -> bf16 (1024 threads) ============
__global__ __launch_bounds__(1024) void k_ce_dlog(const float* __restrict__ out, const int* __restrict__ x,
    unsigned short* __restrict__ dlog, int chunk)
{
  __shared__ unsigned short eb[32000];
  __shared__ float red[16];
  int n = blockIdx.x, tid = threadIdx.x;
  int lane = tid&63, w = tid>>6;
  int b = n>>6, t = n&63;
  int R = b*256 + chunk*64 + t;
  int tgt = x[b*257 + chunk*64 + t + 1];
  const float* row = out + (size_t)R*32000;

  float mx = -3.4e38f;
  for(int v=tid; v<32000; v+=1024){ float l=row[v]; mx=fmaxf(mx,l); eb[v]=f2b(l); }
  #pragma unroll
  for(int off=32;off;off>>=1) mx = fmaxf(mx, __shfl_xor(mx,off));
  if(lane==0) red[w]=mx;
  __syncthreads();
  float m = red[0];
  #pragma unroll
  for(int i=1;i<16;i++) m = fmaxf(m, red[i]);
  __syncthreads();

  float s=0;
  for(int v=tid; v<32000; v+=1024){ float e = expf(b2f(eb[v])-m); s+=e; eb[v]=f2b(e); }
  #pragma unroll
  for(int off=32;off;off>>=1) s += __shfl_xor(s,off);
  if(lane==0) red[w]=s;
  __syncthreads();
  float tot = 0.f;
  #pragma unroll
  for(int i=0;i<16;i++) tot += red[i];
  float iz = 1.f/tot * (1.f/256.f);

  unsigned short* dr = dlog + (size_t)n*32000;
  for(int v=tid; v<32000; v+=1024){
    float a = b2f(eb[v])*iz;
    if(v==tgt) a -= (1.f/256.f);
    dr[v] = f2b(a);
  }
}

extern "C" void kernel_launch(void* const* d_in, const int* in_sizes, int n_in,
                              void* d_out, int out_size, void* d_ws, size_t ws_size,
                              hipStream_t stream)
{
  const int*   x      = (const int*)d_in[0];
  const float* embed  = (const float*)d_in[1];
  const float* pos    = (const float*)d_in[2];
  const float* ln1_g  = (const float*)d_in[3];
  const float* ln1_b  = (const float*)d_in[4];
  const float* qkv_w  = (const float*)d_in[5];
  const float* qkv_b  = (const float*)d_in[6];
  const float* proj_w = (const float*)d_in[7];
  const float* proj_b = (const float*)d_in[8];
  const float* ln2_g  = (const float*)d_in[9];
  const float* ln2_b  = (const float*)d_in[10];
  const float* mlp_w1 = (const float*)d_in[11];
  const float* mlp_b1 = (const float*)d_in[12];
  const float* mlp_w2 = (const float*)d_in[13];
  const float* mlp_b2 = (const float*)d_in[14];
  const float* lnf_g  = (const float*)d_in[15];
  const float* lnf_b  = (const float*)d_in[16];
  const float* head_w = (const float*)d_in[17];
  const float* head_b = (const float*)d_in[18];
  float* out = (float*)d_out;

  char* base = (char*)d_ws;
  size_t off = 0;
  auto AB = [&](size_t bytes)->char*{ char* p = base + off; off += (bytes + 255) & ~(size_t)255; return p; };
  // fp32
  float* W1c  = (float*)AB(16777216);
  float* W2c  = (float*)AB(16777216);
  float* B1c  = (float*)AB(32768);
  float* B2c  = (float*)AB(8192);
  float* hin  = (float*)AB(5*524288);
  float* h1s  = (float*)AB(4*524288);
  float* z1s  = (float*)AB(4*2097152);
  float* dhA  = (float*)AB(524288);
  float* dhB  = (float*)AB(524288);
  float* dxn  = (float*)AB(524288);
  float* dpart= (float*)AB(50*524288);
  float* stats= (float*)AB(4*9*2*256*4);
  // bf16
  unsigned short* qkvwB = (unsigned short*)AB(6291456);
  unsigned short* qkvwT = (unsigned short*)AB(6291456);
  unsigned short* projwB= (unsigned short*)AB(2097152);
  unsigned short* projwT= (unsigned short*)AB(2097152);
  unsigned short* headwB= (unsigned short*)AB(32768000);
  unsigned short* headwT= (unsigned short*)AB(32768000);
  unsigned short* W1b   = (unsigned short*)AB(8388608);
  unsigned short* W1t   = (unsigned short*)AB(8388608);
  unsigned short* W2b   = (unsigned short*)AB(8388608);
  unsigned short* W2t   = (unsigned short*)AB(8388608);
  unsigned short* z1gs  = (unsigned short*)AB(4194304);
  unsigned short* qkBs  = (unsigned short*)AB(4*786432);
  unsigned short* apBs  = (unsigned short*)AB(4*262144);
  unsigned short* obufB = (unsigned short*)AB(262144);
  unsigned short* dlogB = (unsigned short*)AB(16384000);
  unsigned short* dhbB  = (unsigned short*)AB(4*262144);
  unsigned short* dz1bs = (unsigned short*)AB(4*1048576);
  unsigned short* dqkvB = (unsigned short*)AB(786432);

  auto SS1 = [&](int c, int s)->float*{ return stats + ((size_t)(c*9+s)*2)*256; };
  auto SS2 = [&](int c, int s)->float*{ return stats + ((size_t)(c*9+s)*2)*256 + 256; };

  k_setup<<<72,256,0,stream>>>(stats, B1c, mlp_b1, B2c, mlp_b2);
  k_cvt_t<<<dim3(24,8,4),256,0,stream>>>(qkv_w, qkvwT, qkvwB, nullptr, 512, 1536);
  k_cvt_t<<<dim3(8,8,4),256,0,stream>>>(proj_w, projwT, projwB, nullptr, 512, 512);
  k_cvt_t<<<dim3(500,8,1),256,0,stream>>>(head_w, headwT, headwB, nullptr, 512, 32000);
  k_cvt_t<<<dim3(32,8,4),256,0,stream>>>(mlp_w1, W1t, W1b, W1c, 512, 2048);
  k_cvt_t<<<dim3(8,32,4),256,0,stream>>>(mlp_w2, W2t, W2b, W2c, 2048, 512);

  for(int c=0;c<4;c++){
    // ---------------- forward ----------------
    k_embed<<<256,256,0,stream>>>(x, embed, pos, hin, SS1(c,0), SS2(c,0), c);
    for(int i=0;i<4;i++){
      float* h0 = hin + (size_t)i*131072;
      float* h2 = hin + (size_t)(i+1)*131072;
      float* h1 = h1s + (size_t)i*131072;
      float* z1 = z1s + (size_t)i*524288;
      unsigned short* z1g = z1gs + (size_t)i*524288;
      unsigned short* qkB = qkBs + (size_t)i*393216;
      unsigned short* apB = apBs + (size_t)i*131072;
      k_qkv_attn<<<dim3(8,4),512,0,stream>>>(h0, SS1(c,i), SS2(c,i), ln1_g+i*512, ln1_b+i*512,
          qkvwT+(size_t)i*786432, qkv_b+i*1536, qkB, obufB, apB);
      k_nt32<0,1,0><<<dim3(16,8),256,0,stream>>>(obufB, nullptr, nullptr, nullptr, nullptr, nullptr,
          projwT+(size_t)i*262144, proj_b+i*512, h0, nullptr,
          h1, nullptr, SS1(c,5+i), SS2(c,5+i),
          nullptr, nullptr, nullptr, nullptr, 256,512,512, 8, 0);
      k_nt32<1,0,0><<<dim3(64,8),256,0,stream>>>(nullptr, h1, SS1(c,5+i), SS2(c,5+i), ln2_g+i*512, ln2_b+i*512,
          W1t+(size_t)i*1048576, B1c+i*2048, nullptr, nullptr,
          z1, z1g, nullptr, nullptr,
          nullptr, nullptr, nullptr, nullptr, 256,2048,512, 8, 1);
      k_nt32<0,1,0><<<dim3(16,8),256,0,stream>>>(z1g, nullptr, nullptr, nullptr, nullptr, nullptr,
          W2t+(size_t)i*1048576, B2c+i*512, h1, nullptr,
          h2, nullptr, SS1(c,i+1), SS2(c,i+1),
          nullptr, nullptr, nullptr, nullptr, 256,512,2048, 32, 0);
    }
    k_nt<128,1,0><<<dim3(250,2),256,0,stream>>>(nullptr, hin+4*131072, SS1(c,4), SS2(c,4), lnf_g, lnf_b,
        headwT, head_b, nullptr, nullptr,
        out, nullptr, nullptr, nullptr, 256,32000,512, 8, 0, c);

    // ---------------- backward ----------------
    k_ce_dlog<<<256,1024,0,stream>>>(out, x, dlogB, c);
    k_nt<128,0,0><<<dim3(4,2,50),256,0,stream>>>(dlogB, nullptr, nullptr, nullptr, nullptr, nullptr,
        headwB, nullptr, nullptr, nullptr,
        dpart, nullptr, nullptr, nullptr, 256,512,32000, 10, 0, -1);
    k_ln_bwd<<<256,256,0,stream>>>(nullptr, dpart, 50, hin+4*131072, lnf_g, SS1(c,4), SS2(c,4),
        nullptr, dhA, dhbB + 3*131072);
    for(int i=3;i>=0;i--){
      float* h0 = hin + (size_t)i*131072;
      float* h1 = h1s + (size_t)i*131072;
      float* z1 = z1s + (size_t)i*524288;
      unsigned short* qkB = qkBs + (size_t)i*393216;
      unsigned short* apB = apBs + (size_t)i*131072;
      // dz1 = (dh2 @ W2) * gelu_df(z1); for i<3 dh2 is computed in-staging (LN1-bwd of layer i+1)
      if(i==3){
        k_nt32<0,0,0><<<dim3(64,8),256,0,stream>>>(dhbB + 3*131072, nullptr, nullptr, nullptr, nullptr, nullptr,
            W2b+(size_t)i*1048576, nullptr, nullptr, z1,
            nullptr, dz1bs + (size_t)i*524288, nullptr, nullptr,
            nullptr, nullptr, nullptr, nullptr, 256,2048,512, 8, 0);
      } else {
        k_nt32<0,0,1><<<dim3(64,8),256,0,stream>>>(nullptr, hin + (size_t)(i+1)*131072,
            SS1(c,i+1), SS2(c,i+1), ln1_g+(i+1)*512, nullptr,
            W2b+(size_t)i*1048576, nullptr, nullptr, z1,
            nullptr, dz1bs + (size_t)i*524288, nullptr, nullptr,
            dxn, dhB, dhA, dhbB + (size_t)i*131072, 256,2048,512, 8, 0);
      }
      // dxn2 = dz1 @ W1
      k_nt32<0,0,0><<<dim3(16,8),256,0,stream>>>(dz1bs + (size_t)i*524288, nullptr, nullptr, nullptr, nullptr, nullptr,
          W1b+(size_t)i*1048576, nullptr, nullptr, nullptr,
          dxn, nullptr, nullptr, nullptr,
          nullptr, nullptr, nullptr, nullptr, 256,512,2048, 32, 0);
      // fused LN2-bwd + do-GEMM + attention backward
      k_do_attn<<<dim3(8,4),512,0,stream>>>(dxn, h1, ln2_g+i*512, SS1(c,5+i), SS2(c,5+i),
          dhA, dhB, projwB+(size_t)i*262144, qkB, apB, dqkvB);
      // dxn1 = dqkv @ qkv_w
      k_nt32<0,0,0><<<dim3(16,8),256,0,stream>>>(dqkvB, nullptr, nullptr, nullptr, nullptr, nullptr,
          qkvwB+(size_t)i*786432, nullptr, nullptr, nullptr,
          dxn, nullptr, nullptr, nullptr,
          nullptr, nullptr, nullptr, nullptr, 256,512,1536, 24, 0);
    }
    k_sgd_all<<<2048,256,0,stream>>>(z1gs, dhbB, dz1bs, h1s, stats, c,
        W1c, W1b, W1t, B1c, W2c, W2b, W2t, B2c, ln2_g, ln2_b);
  }
}

// Round 11
// 2184.818 us; speedup vs baseline: 1.1816x; 1.1816x over previous
//
#include <hip/hip_runtime.h>
#include <cstddef>

#define LRATE 3e-4f

typedef short short8 __attribute__((ext_vector_type(8)));
typedef float f32x4 __attribute__((ext_vector_type(4)));
typedef __bf16 bf16x8 __attribute__((ext_vector_type(8)));

__device__ __forceinline__ unsigned short f2b(float f){
  unsigned u = __builtin_bit_cast(unsigned, f);
  unsigned r = (u + 0x7fffu + ((u>>16)&1u)) >> 16;
  return (unsigned short)r;
}
__device__ __forceinline__ float b2f(unsigned short s){
  unsigned u = ((unsigned)s)<<16;
  return __builtin_bit_cast(float, u);
}
__device__ __forceinline__ float gelu_f(float x){
  float u = 0.7978845608028654f*(x + 0.044715f*x*x*x);
  float t = tanhf(u);
  return 0.5f*x*(1.f+t);
}
__device__ __forceinline__ float gelu_df(float x){
  float x2 = x*x;
  float u = 0.7978845608028654f*(x + 0.044715f*x*x2);
  float t = tanhf(u);
  return 0.5f*(1.f+t) + 0.5f*x*(1.f-t*t)*0.7978845608028654f*(1.f+0.134145f*x2);
}
__device__ __forceinline__ void gll16(const void* g, void* l){
  __builtin_amdgcn_global_load_lds(
      (const __attribute__((address_space(1))) unsigned int*)(g),
      (__attribute__((address_space(3))) unsigned int*)(l), 16, 0, 0);
}
__device__ __forceinline__ bf16x8 frag_read(const short* base, int row, int h, int kg){
  int c = (h*4+kg) ^ (row&7);
  return __builtin_bit_cast(bf16x8, *(const short8*)((const char*)base + row*128 + c*16));
}
__device__ __forceinline__ void tr_write(short* base, int nrow, int k, unsigned short v){
  *(short*)((char*)base + nrow*128 + (((k>>3)^(nrow&7))<<4) + (k&7)*2) = (short)v;
}

// ============ TILE=128 NT bf16 MFMA GEMM, 2-phase pipelined (head fwd/bwd only) ============
template<int TILE, int LNA, int STATS>
__global__ __launch_bounds__(256) void k_nt(
    const unsigned short* __restrict__ Ag,
    const float* __restrict__ Af, const float* __restrict__ aS1, const float* __restrict__ aS2,
    const float* __restrict__ lng, const float* __restrict__ lnb,
    const unsigned short* __restrict__ Bg,
    const float* __restrict__ bias, const float* __restrict__ resid, const float* __restrict__ zsrc,
    float* __restrict__ outf, unsigned short* __restrict__ outb,
    float* __restrict__ oS1, float* __restrict__ oS2,
    int M, int N, int K, int k_iters, int gelu_b, int remap_c)
{
  constexpr int F = TILE/32;
  constexpr int CH = TILE/32;
  __shared__ __align__(16) short Asm[2*TILE*64];
  __shared__ __align__(16) short Bsm[2*TILE*64];
  int tid=threadIdx.x, lane=tid&63, w=tid>>6;
  int wr=w>>1, wc=w&1, r16=lane&15, kg=lane>>4;
  int bn=blockIdx.x*TILE, bm=blockIdx.y*TILE;
  int kbase = blockIdx.z*k_iters*64;
  f32x4 acc[F][F]={};

  int ids[CH], rows[CH];
  float mA[CH], rA[CH];
  #pragma unroll
  for(int q=0;q<CH;q++){ ids[q]=w*(TILE*2)+q*64+lane; rows[q]=ids[q]>>3; }
  if constexpr(LNA){
    #pragma unroll
    for(int q=0;q<CH;q++){
      float s1=aS1[bm+rows[q]], s2=aS2[bm+rows[q]];
      float mm=s1*(1.f/512.f);
      mA[q]=mm; rA[q]=rsqrtf(s2*(1.f/512.f)-mm*mm+1e-5f);
    }
  }

  auto STAGE=[&](int t,int buf){
    int k0 = kbase + t*64;
    short* Ad = Asm + buf*TILE*64;
    short* Bd = Bsm + buf*TILE*64;
    if constexpr(LNA==0){
      #pragma unroll
      for(int q=0;q<CH;q++){
        int gc=(ids[q]&7)^(rows[q]&7);
        gll16(Ag + (size_t)(bm+rows[q])*K + k0 + gc*8, (char*)Ad + ids[q]*16);
      }
    } else {
      #pragma unroll
      for(int q=0;q<CH;q++){
        int gc=(ids[q]&7)^(rows[q]&7);
        const float* src = Af + (size_t)(bm+rows[q])*K + k0 + gc*8;
        float4 v0=*(const float4*)src, v1=*(const float4*)(src+4);
        const float* gp=lng+k0+gc*8; const float* bp=lnb+k0+gc*8;
        float4 g0=*(const float4*)gp, g1=*(const float4*)(gp+4);
        float4 c0=*(const float4*)bp, c1=*(const float4*)(bp+4);
        float mm=mA[q], rr=rA[q];
        short8 o;
        o[0]=(short)f2b((v0.x-mm)*rr*g0.x+c0.x);
        o[1]=(short)f2b((v0.y-mm)*rr*g0.y+c0.y);
        o[2]=(short)f2b((v0.z-mm)*rr*g0.z+c0.z);
        o[3]=(short)f2b((v0.w-mm)*rr*g0.w+c0.w);
        o[4]=(short)f2b((v1.x-mm)*rr*g1.x+c1.x);
        o[5]=(short)f2b((v1.y-mm)*rr*g1.y+c1.y);
        o[6]=(short)f2b((v1.z-mm)*rr*g1.z+c1.z);
        o[7]=(short)f2b((v1.w-mm)*rr*g1.w+c1.w);
        *(short8*)((char*)Ad + ids[q]*16) = o;
      }
    }
    #pragma unroll
    for(int q=0;q<CH;q++){
      int gc=(ids[q]&7)^(rows[q]&7);
      gll16(Bg + (size_t)(bn+rows[q])*K + k0 + gc*8, (char*)Bd + ids[q]*16);
    }
  };

  STAGE(0,0);
  for(int t=0;t<k_iters;++t){
    int buf=t&1;
    STAGE(t+1<k_iters?t+1:t, buf^1);
    asm volatile("" ::: "memory");
    constexpr int VMC = LNA ? (TILE/32) : (TILE/16);
    if constexpr(VMC==2)      asm volatile("s_waitcnt vmcnt(2)" ::: "memory");
    else if constexpr(VMC==4) asm volatile("s_waitcnt vmcnt(4)" ::: "memory");
    else                      asm volatile("s_waitcnt vmcnt(8)" ::: "memory");
    __builtin_amdgcn_sched_barrier(0);
    __builtin_amdgcn_s_barrier();
    asm volatile("" ::: "memory");
    const char* Ab=(const char*)(Asm+buf*TILE*64);
    const char* Bb=(const char*)(Bsm+buf*TILE*64);
    #pragma unroll
    for(int h=0;h<2;h++){
      bf16x8 af[F], bfr[F];
      #pragma unroll
      for(int fa=0;fa<F;fa++){
        int row=wr*(TILE/2)+fa*16+r16;
        int c=(h*4+kg)^(row&7);
        af[fa]=__builtin_bit_cast(bf16x8, *(const short8*)(Ab + row*128 + c*16));
      }
      #pragma unroll
      for(int fb=0;fb<F;fb++){
        int row=wc*(TILE/2)+fb*16+r16;
        int c=(h*4+kg)^(row&7);
        bfr[fb]=__builtin_bit_cast(bf16x8, *(const short8*)(Bb + row*128 + c*16));
      }
      #pragma unroll
      for(int fa=0;fa<F;fa++)
        #pragma unroll
        for(int fb=0;fb<F;fb++)
          acc[fa][fb]=__builtin_amdgcn_mfma_f32_16x16x32_bf16(af[fa],bfr[fb],acc[fa][fb],0,0,0);
    }
    asm volatile("s_waitcnt lgkmcnt(0)" ::: "memory");
    __builtin_amdgcn_sched_barrier(0);
    __builtin_amdgcn_s_barrier();
    asm volatile("" ::: "memory");
  }
  asm volatile("s_waitcnt vmcnt(0)" ::: "memory");

  int rb = lane>>4;
  float st1[F][4]={}, st2[F][4]={};
  #pragma unroll
  for(int fa=0; fa<F; fa++){
    #pragma unroll
    for(int fb=0; fb<F; fb++){
      f32x4 av = acc[fa][fb];
      #pragma unroll
      for(int i=0;i<4;i++){
        int m = bm + wr*(TILE/2) + fa*16 + rb*4 + i;
        int n = bn + wc*(TILE/2) + fb*16 + r16;
        float v = av[i];
        if(bias) v += bias[n];
        if(resid) v += resid[(size_t)m*N + n];
        if(zsrc) v *= gelu_df(zsrc[(size_t)m*N + n]);
        if constexpr(STATS){ st1[fa][i] += v; st2[fa][i] += v*v; }
        int mo = (remap_c>=0)? ((m>>6)*256 + remap_c*64 + (m&63)) : m;
        if(outf) outf[(size_t)blockIdx.z*M*N + (size_t)mo*N + n] = v;
        if(outb) outb[(size_t)mo*N + n] = f2b(gelu_b ? gelu_f(v) : v);
      }
    }
  }
  if constexpr(STATS){
    #pragma unroll
    for(int fa=0; fa<F; fa++){
      #pragma unroll
      for(int i=0;i<4;i++){
        float s1 = st1[fa][i], s2 = st2[fa][i];
        #pragma unroll
        for(int msk=1; msk<16; msk<<=1){ s1 += __shfl_xor(s1,msk); s2 += __shfl_xor(s2,msk); }
        if(r16==0){
          int m = bm + wr*(TILE/2) + fa*16 + rb*4 + i;
          atomicAdd(&oS1[m], s1);
          atomicAdd(&oS2[m], s2);
        }
      }
    }
  }
}

// ============ TILE=32 NT GEMM, 8-slot rolling prefetch (PF=6) ============
template<int LNA, int STATS>
__global__ __launch_bounds__(256) void k_nt32(
    const unsigned short* __restrict__ Ag,
    const float* __restrict__ Af, const float* __restrict__ aS1, const float* __restrict__ aS2,
    const float* __restrict__ lng, const float* __restrict__ lnb,
    const unsigned short* __restrict__ Bg,
    const float* __restrict__ bias, const float* __restrict__ resid, const float* __restrict__ zsrc,
    float* __restrict__ outf, unsigned short* __restrict__ outb,
    float* __restrict__ oS1, float* __restrict__ oS2,
    int M, int N, int K, int k_iters, int gelu_b)
{
  __shared__ __align__(16) short Asl[8*2048];
  __shared__ __align__(16) short Bsl[8*2048];
  int tid=threadIdx.x, lane=tid&63, w=tid>>6;
  int wr=w>>1, wc=w&1, r16=lane&15, kg=lane>>4;
  int bn=blockIdx.x*32, bm=blockIdx.y*32;
  int row=tid>>3, s8=tid&7, gc=s8^(row&7);
  f32x4 acc={0.f,0.f,0.f,0.f};

  auto ISSUE_A=[&](int t,int slot){
    gll16(Ag + (size_t)(bm+row)*K + t*64 + gc*8, (char*)Asl + slot*4096 + tid*16);
  };
  auto ISSUE_B=[&](int t,int slot){
    gll16(Bg + (size_t)(bn+row)*K + t*64 + gc*8, (char*)Bsl + slot*4096 + tid*16);
  };

  if constexpr(LNA){
    float mm, rr;
    { float a=aS1[bm+row], b=aS2[bm+row]; mm=a*(1.f/512.f); rr=rsqrtf(b*(1.f/512.f)-mm*mm+1e-5f); }
    for(int t=0;t<k_iters;t++){
      const float* src = Af + (size_t)(bm+row)*K + t*64 + gc*8;
      float4 v0=*(const float4*)src, v1=*(const float4*)(src+4);
      const float* gp=lng+t*64+gc*8; const float* bp=lnb+t*64+gc*8;
      float4 g0=*(const float4*)gp, g1=*(const float4*)(gp+4);
      float4 c0=*(const float4*)bp, c1=*(const float4*)(bp+4);
      short8 o;
      o[0]=(short)f2b((v0.x-mm)*rr*g0.x+c0.x);
      o[1]=(short)f2b((v0.y-mm)*rr*g0.y+c0.y);
      o[2]=(short)f2b((v0.z-mm)*rr*g0.z+c0.z);
      o[3]=(short)f2b((v0.w-mm)*rr*g0.w+c0.w);
      o[4]=(short)f2b((v1.x-mm)*rr*g1.x+c1.x);
      o[5]=(short)f2b((v1.y-mm)*rr*g1.y+c1.y);
      o[6]=(short)f2b((v1.z-mm)*rr*g1.z+c1.z);
      o[7]=(short)f2b((v1.w-mm)*rr*g1.w+c1.w);
      *(short8*)((char*)Asl + t*4096 + tid*16) = o;
    }
  }

  #pragma unroll
  for(int s=0;s<6;s++){
    if constexpr(LNA==0) ISSUE_A(s, s);
    ISSUE_B(s, s);
  }
  if constexpr(LNA){
    asm volatile("s_waitcnt lgkmcnt(0)" ::: "memory");
    __builtin_amdgcn_sched_barrier(0);
    __builtin_amdgcn_s_barrier();
  }

  for(int t=0;t<k_iters;++t){
    int tt = (t+6<k_iters)? t+6 : k_iters-1;
    int slot=(t+6)&7;
    if constexpr(LNA==0) ISSUE_A(tt, slot);
    ISSUE_B(tt, slot);
    if constexpr(LNA==0) asm volatile("s_waitcnt vmcnt(12)" ::: "memory");
    else                 asm volatile("s_waitcnt vmcnt(6)" ::: "memory");
    __builtin_amdgcn_sched_barrier(0);
    __builtin_amdgcn_s_barrier();
    __builtin_amdgcn_sched_barrier(0);
    const char* Ab = LNA ? (const char*)Asl + t*4096 : (const char*)Asl + (t&7)*4096;
    const char* Bb = (const char*)Bsl + (t&7)*4096;
    #pragma unroll
    for(int h=0;h<2;h++){
      int rowa=wr*16+r16, ca=(h*4+kg)^(rowa&7);
      bf16x8 a=__builtin_bit_cast(bf16x8, *(const short8*)(Ab + rowa*128 + ca*16));
      int rowb=wc*16+r16, cb=(h*4+kg)^(rowb&7);
      bf16x8 b=__builtin_bit_cast(bf16x8, *(const short8*)(Bb + rowb*128 + cb*16));
      acc=__builtin_amdgcn_mfma_f32_16x16x32_bf16(a,b,acc,0,0,0);
    }
    asm volatile("s_waitcnt lgkmcnt(0)" ::: "memory");
    __builtin_amdgcn_sched_barrier(0);
  }
  asm volatile("s_waitcnt vmcnt(0)" ::: "memory");

  int rb=lane>>4;
  float st1[4]={}, st2[4]={};
  #pragma unroll
  for(int i=0;i<4;i++){
    int m = bm + wr*16 + rb*4 + i;
    int n = bn + wc*16 + r16;
    float v = acc[i];
    if(bias) v += bias[n];
    if(resid) v += resid[(size_t)m*N + n];
    if(zsrc) v *= gelu_df(zsrc[(size_t)m*N + n]);
    if constexpr(STATS){ st1[i]=v; st2[i]=v*v; }
    if(outf) outf[(size_t)m*N + n] = v;
    if(outb) outb[(size_t)m*N + n] = f2b(gelu_b ? gelu_f(v) : v);
  }
  if constexpr(STATS){
    #pragma unroll
    for(int i=0;i<4;i++){
      float s1=st1[i], s2=st2[i];
      #pragma unroll
      for(int msk=1;msk<16;msk<<=1){ s1+=__shfl_xor(s1,msk); s2+=__shfl_xor(s2,msk); }
      if(r16==0){
        int m = bm + wr*16 + rb*4 + i;
        atomicAdd(&oS1[m], s1);
        atomicAdd(&oS2[m], s2);
      }
    }
  }
}

// ============ TN wgrad + SGD body ============
template<int LNA>
__device__ __forceinline__ void sgd_body(
    const unsigned short* __restrict__ Ag,
    const float* __restrict__ Af, const float* __restrict__ aS1, const float* __restrict__ aS2,
    const float* __restrict__ lng, const float* __restrict__ lnb,
    const unsigned short* __restrict__ Bg,
    float* __restrict__ Wf, unsigned short* __restrict__ Wb, unsigned short* __restrict__ Wt,
    float* __restrict__ bv, int M, int N, int bm, int bn,
    short* Asm, short* Bsm, short* Tsm)
{
  int tid = threadIdx.x;
  f32x4 acc00={},acc01={},acc10={},acc11={};
  int lane = tid&63, w = tid>>6, wr = w>>1, wc = w&1;
  int r16 = lane&15, kg = lane>>4;
  float gv[8], bvv[8];
  if constexpr(LNA){
    int ms=(tid&7)*8;
    #pragma unroll
    for(int j=0;j<8;j++){ gv[j]=lng[bm+ms+j]; bvv[j]=lnb[bm+ms+j]; }
  }
  float csum = 0.f;
  int docs = (bv && bm==0 && tid<64);
  for(int k0=0; k0<256; k0+=32){
    if constexpr(LNA==0){
      int kk = tid>>3, ms=(tid&7)*8;
      short8 v = *(const short8*)(Ag + (size_t)(k0+kk)*M + bm + ms);
      #pragma unroll
      for(int j=0;j<8;j++){ int row=ms+j; Asm[row*40 + (((kk>>3)^((row>>3)&3))<<3) + (kk&7)] = v[j]; }
    } else {
      int kk = tid>>3, ms=(tid&7)*8;
      int token = k0+kk;
      float s1=aS1[token], s2=aS2[token];
      float mm=s1*(1.f/512.f);
      float rr=rsqrtf(s2*(1.f/512.f)-mm*mm+1e-5f);
      const float* src = Af + (size_t)token*M + bm + ms;
      float4 v0=*(const float4*)src, v1=*(const float4*)(src+4);
      float vals[8]={v0.x,v0.y,v0.z,v0.w,v1.x,v1.y,v1.z,v1.w};
      #pragma unroll
      for(int j=0;j<8;j++){
        int row=ms+j;
        Asm[row*40 + (((kk>>3)^((row>>3)&3))<<3) + (kk&7)] = (short)f2b((vals[j]-mm)*rr*gv[j]+bvv[j]);
      }
    }
    { int kk = tid>>3, ns=(tid&7)*8;
      short8 v = *(const short8*)(Bg + (size_t)(k0+kk)*N + bn + ns);
      #pragma unroll
      for(int j=0;j<8;j++){ int row=ns+j; Bsm[row*40 + (((kk>>3)^((row>>3)&3))<<3) + (kk&7)] = v[j]; } }
    __syncthreads();
    if(docs){
      #pragma unroll
      for(int kk2=0;kk2<32;kk2++)
        csum += b2f((unsigned short)Bsm[tid*40 + (((kk2>>3)^((tid>>3)&3))<<3) + (kk2&7)]);
    }
    int ra0 = wr*32 + r16, ra1 = ra0+16, rb0 = wc*32 + r16, rb1 = rb0+16;
    bf16x8 a0 = __builtin_bit_cast(bf16x8, *(const short8*)(Asm + ra0*40 + ((kg ^ ((ra0>>3)&3))<<3)));
    bf16x8 a1 = __builtin_bit_cast(bf16x8, *(const short8*)(Asm + ra1*40 + ((kg ^ ((ra1>>3)&3))<<3)));
    bf16x8 b0 = __builtin_bit_cast(bf16x8, *(const short8*)(Bsm + rb0*40 + ((kg ^ ((rb0>>3)&3))<<3)));
    bf16x8 b1 = __builtin_bit_cast(bf16x8, *(const short8*)(Bsm + rb1*40 + ((kg ^ ((rb1>>3)&3))<<3)));
    acc00 = __builtin_amdgcn_mfma_f32_16x16x32_bf16(a0, b0, acc00, 0,0,0);
    acc01 = __builtin_amdgcn_mfma_f32_16x16x32_bf16(a0, b1, acc01, 0,0,0);
    acc10 = __builtin_amdgcn_mfma_f32_16x16x32_bf16(a1, b0, acc10, 0,0,0);
    acc11 = __builtin_amdgcn_mfma_f32_16x16x32_bf16(a1, b1, acc11, 0,0,0);
    __syncthreads();
  }
  if(docs) bv[bn+tid] -= LRATE*csum;
  int rb = lane>>4;
  #pragma unroll
  for(int ar=0;ar<2;ar++){
    #pragma unroll
    for(int bc=0;bc<2;bc++){
      f32x4 av = (ar==0) ? (bc==0?acc00:acc01) : (bc==0?acc10:acc11);
      #pragma unroll
      for(int i=0;i<4;i++){
        int lm = wr*32 + ar*16 + rb*4 + i;
        int ln = wc*32 + bc*16 + r16;
        size_t oi = (size_t)(bm+lm)*N + bn+ln;
        float wv = Wf[oi] - LRATE*av[i];
        Wf[oi] = wv;
        unsigned short ub = f2b(wv);
        Wb[oi] = ub;
        Tsm[ln*72 + lm] = (short)ub;
      }
    }
  }
  __syncthreads();
  #pragma unroll
  for(int q=0;q<2;q++){
    int id = tid*2+q;
    int ln = id>>3, ch = id&7;
    short8 vv = *(const short8*)(Tsm + ln*72 + ch*8);
    *(short8*)(Wt + (size_t)(bn+ln)*M + bm + ch*8) = vv;
  }
}

__global__ __launch_bounds__(256) void k_sgd_all(
    const unsigned short* __restrict__ z1gs, const unsigned short* __restrict__ dh2bB,
    const unsigned short* __restrict__ dz1bs, const float* __restrict__ h1s,
    const float* __restrict__ stats, int c,
    float* W1c, unsigned short* W1b, unsigned short* W1t, float* B1c,
    float* W2c, unsigned short* W2b, unsigned short* W2t, float* B2c,
    const float* __restrict__ ln2_g, const float* __restrict__ ln2_b)
{
  __shared__ __align__(16) short Asm[64*40], Bsm[64*40], Tsm[64*72];
  int gid = blockIdx.x;
  int i = gid>>9, r = gid&511;
  if(r<256){
    int bn=(r&7)*64, bm=(r>>3)*64;
    sgd_body<0>(z1gs+(size_t)i*524288, nullptr,nullptr,nullptr,nullptr,nullptr,
        dh2bB+(size_t)i*131072,
        W2c+(size_t)i*1048576, W2b+(size_t)i*1048576, W2t+(size_t)i*1048576, B2c+i*512,
        2048, 512, bm, bn, Asm,Bsm,Tsm);
  } else {
    int r2=r-256;
    int bn=(r2&31)*64, bm=(r2>>5)*64;
    const float* S1 = stats + ((size_t)(c*9+5+i)*2)*256;
    sgd_body<1>(nullptr, h1s+(size_t)i*131072, S1, S1+256, ln2_g+i*512, ln2_b+i*512,
        dz1bs+(size_t)i*524288,
        W1c+(size_t)i*1048576, W1b+(size_t)i*1048576, W1t+(size_t)i*1048576, B1c+i*2048,
        512, 2048, bm, bn, Asm,Bsm,Tsm);
  }
}

// ============ transpose-convert ============
__global__ __launch_bounds__(256) void k_cvt_t(const float* __restrict__ src,
    unsigned short* __restrict__ dstT, unsigned short* __restrict__ dstO, float* __restrict__ dstF,
    int R, int C)
{
  __shared__ __align__(16) short T[64*72];
  size_t zoff = (size_t)blockIdx.z * R * C;
  int c0 = blockIdx.x*64, r0 = blockIdx.y*64;
  int tid = threadIdx.x;
  #pragma unroll
  for(int q=0;q<16;q++){
    int e = tid + q*256;
    int r = e>>6, cc = e&63;
    float v = src[zoff + (size_t)(r0+r)*C + c0+cc];
    unsigned short bvu = f2b(v);
    T[cc*72 + r] = (short)bvu;
    if(dstO) dstO[zoff + (size_t)(r0+r)*C + c0+cc] = bvu;
    if(dstF) dstF[zoff + (size_t)(r0+r)*C + c0+cc] = v;
  }
  __syncthreads();
  #pragma unroll
  for(int q=0;q<2;q++){
    int id = tid*2+q;
    int cc = id>>3, ch = id&7;
    short8 vv = *(const short8*)(T + cc*72 + ch*8);
    *(short8*)(dstT + zoff + (size_t)(c0+cc)*R + r0 + ch*8) = vv;
  }
}

// ============ setup ============
__global__ __launch_bounds__(256) void k_setup(float* stats, float* B1c, const float* b1,
    float* B2c, const float* b2)
{
  int i = blockIdx.x*256 + threadIdx.x;
  if(i < 18432) stats[i] = 0.f;
  if(i < 8192)  B1c[i] = b1[i];
  if(i < 2048)  B2c[i] = b2[i];
}

// ============ embed + pos (+ LN stats) ============
__global__ __launch_bounds__(256) void k_embed(const int* __restrict__ x, const float* __restrict__ emb,
    const float* __restrict__ pos, float* __restrict__ h, float* __restrict__ S1, float* __restrict__ S2, int chunk)
{
  int n = blockIdx.x, tid = threadIdx.x;
  int b = n>>6, t = n&63;
  int tok = x[b*257 + chunk*64 + t];
  size_t b0 = (size_t)n*512 + tid;
  float v0 = emb[(size_t)tok*512 + tid]       + pos[t*512 + tid];
  float v1 = emb[(size_t)tok*512 + tid + 256] + pos[t*512 + tid + 256];
  h[b0] = v0; h[b0+256] = v1;
  __shared__ float r1[256], r2[256];
  r1[tid] = v0+v1; r2[tid] = v0*v0+v1*v1;
  __syncthreads();
  for(int o=128;o;o>>=1){ if(tid<o){ r1[tid]+=r1[tid+o]; r2[tid]+=r2[tid+o]; } __syncthreads(); }
  if(tid==0){ S1[n]=r1[0]; S2[n]=r2[0]; }
}

// ============ LayerNorm bwd (wave-shuffle reductions; nz>0 sums split-K parts) ============
__global__ __launch_bounds__(256) void k_ln_bwd(const float* __restrict__ dy, const float* __restrict__ dp, int nz,
    const float* __restrict__ x, const float* __restrict__ g,
    const float* __restrict__ S1v, const float* __restrict__ S2v,
    const float* __restrict__ addin, float* __restrict__ dx, unsigned short* __restrict__ dxb)
{
  int n = blockIdx.x, tid = threadIdx.x;
  int lane = tid&63, w4 = tid>>6;
  float s1 = S1v[n], s2 = S2v[n];
  float m = s1*(1.f/512.f);
  float r = rsqrtf(s2*(1.f/512.f) - m*m + 1e-5f);
  size_t b0 = (size_t)n*512 + tid;
  float dy0, dy1;
  if(nz){
    dy0=0.f; dy1=0.f;
    for(int z=0;z<nz;z++){ dy0 += dp[(size_t)z*131072 + b0]; dy1 += dp[(size_t)z*131072 + b0 + 256]; }
  } else { dy0 = dy[b0]; dy1 = dy[b0+256]; }
  float x0 = x[b0], x1 = x[b0+256];
  float xh0 = (x0-m)*r, xh1 = (x1-m)*r;
  float gh0 = dy0*g[tid], gh1 = dy1*g[tid+256];
  float a1 = gh0+gh1, a2 = gh0*xh0 + gh1*xh1;
  #pragma unroll
  for(int off=32;off;off>>=1){ a1 += __shfl_xor(a1,off); a2 += __shfl_xor(a2,off); }
  __shared__ float rw[8];
  if(lane==0){ rw[w4]=a1; rw[4+w4]=a2; }
  __syncthreads();
  float mg  = (rw[0]+rw[1]+rw[2]+rw[3])*(1.f/512.f);
  float mgx = (rw[4]+rw[5]+rw[6]+rw[7])*(1.f/512.f);
  float d0 = (gh0 - mg - xh0*mgx)*r;
  float d1 = (gh1 - mg - xh1*mgx)*r;
  if(addin){ d0 += addin[b0]; d1 += addin[b0+256]; }
  dx[b0] = d0; dx[b0+256] = d1;
  dxb[b0] = f2b(d0); dxb[b0+256] = f2b(d1);
}

// ============ fused qkv GEMM (LN1 on-the-fly) + attention forward — 512 threads ============
__global__ __launch_bounds__(512) void k_qkv_attn(
    const float* __restrict__ h0, const float* __restrict__ S1, const float* __restrict__ S2,
    const float* __restrict__ lng, const float* __restrict__ lnb,
    const unsigned short* __restrict__ wT, const float* __restrict__ bias,
    unsigned short* __restrict__ qkB, unsigned short* __restrict__ obuf, unsigned short* __restrict__ ap)
{
  __shared__ __align__(16) short Afull[32768];
  __shared__ __align__(16) short Bsl[3*12288];
  short* Qs  = Bsl;
  short* Ks2 = Bsl + 4096;
  short* Vt  = Bsl + 8192;
  short* Pb  = Afull;
  float* Sf  = (float*)(Afull + 8192);
  int hh=blockIdx.x, bb=blockIdx.y;
  int tid=threadIdx.x, lane=tid&63, w=tid>>6;
  int r16=lane&15, kg=lane>>4, rb=lane>>4;

  {
    int arow=tid>>3, as8=tid&7, agc=as8^(arow&7);
    float mm,rr;
    { float a=S1[bb*64+arow], b2=S2[bb*64+arow]; mm=a*(1.f/512.f); rr=rsqrtf(b2*(1.f/512.f)-mm*mm+1e-5f); }
    for(int s=0;s<8;s++){
      const float* src = h0 + (size_t)(bb*64+arow)*512 + s*64 + agc*8;
      float4 v0=*(const float4*)src, v1=*(const float4*)(src+4);
      const float* gp=lng+s*64+agc*8; const float* bp=lnb+s*64+agc*8;
      float4 g0=*(const float4*)gp, g1=*(const float4*)(gp+4);
      float4 c0=*(const float4*)bp, c1=*(const float4*)(bp+4);
      short8 o;
      o[0]=(short)f2b((v0.x-mm)*rr*g0.x+c0.x);
      o[1]=(short)f2b((v0.y-mm)*rr*g0.y+c0.y);
      o[2]=(short)f2b((v0.z-mm)*rr*g0.z+c0.z);
      o[3]=(short)f2b((v0.w-mm)*rr*g0.w+c0.w);
      o[4]=(short)f2b((v1.x-mm)*rr*g1.x+c1.x);
      o[5]=(short)f2b((v1.y-mm)*rr*g1.y+c1.y);
      o[6]=(short)f2b((v1.z-mm)*rr*g1.z+c1.z);
      o[7]=(short)f2b((v1.w-mm)*rr*g1.w+c1.w);
      *(short8*)((char*)(Afull) + s*8192 + tid*16) = o;
    }
  }
  __syncthreads();

  auto STB=[&](int t,int slot){
    #pragma unroll
    for(int q=0;q<3;q++){
      int cid=q*512+tid, brow=cid>>3, s8=cid&7, gc=s8^(brow&7);
      int p=brow>>6, cin=brow&63;
      gll16(wT + (size_t)(p*512+hh*64+cin)*512 + t*64 + gc*8, (char*)Bsl + slot*24576 + cid*16);
    }
  };
  STB(0,0); STB(1,1);
  int wr=w>>2, wc=w&3;
  f32x4 acc[2][3]={};
  for(int t=0;t<8;t++){
    int tt=(t+2<8)? t+2 : 7;
    STB(tt,(t+2)%3);
    asm volatile("s_waitcnt vmcnt(6)" ::: "memory");
    __builtin_amdgcn_sched_barrier(0);
    __builtin_amdgcn_s_barrier();
    __builtin_amdgcn_sched_barrier(0);
    const char* Ab=(const char*)Afull + t*8192;
    const char* Bb=(const char*)Bsl + (t%3)*24576;
    #pragma unroll
    for(int h=0;h<2;h++){
      bf16x8 af[2], bfr[3];
      #pragma unroll
      for(int fa=0;fa<2;fa++){
        int rowa=wr*32+fa*16+r16, ca=(h*4+kg)^(rowa&7);
        af[fa]=__builtin_bit_cast(bf16x8, *(const short8*)(Ab + rowa*128 + ca*16));
      }
      #pragma unroll
      for(int fb=0;fb<3;fb++){
        int rowb=wc*48+fb*16+r16, cb=(h*4+kg)^(rowb&7);
        bfr[fb]=__builtin_bit_cast(bf16x8, *(const short8*)(Bb + rowb*128 + cb*16));
      }
      #pragma unroll
      for(int fa=0;fa<2;fa++)
        #pragma unroll
        for(int fb=0;fb<3;fb++)
          acc[fa][fb]=__builtin_amdgcn_mfma_f32_16x16x32_bf16(af[fa],bfr[fb],acc[fa][fb],0,0,0);
    }
    asm volatile("s_waitcnt lgkmcnt(0)" ::: "memory");
    __builtin_amdgcn_sched_barrier(0);
    __builtin_amdgcn_s_barrier();
    __builtin_amdgcn_sched_barrier(0);
  }
  asm volatile("s_waitcnt vmcnt(0)" ::: "memory");
  __syncthreads();

  #pragma unroll
  for(int fa=0;fa<2;fa++)
    #pragma unroll
    for(int fb=0;fb<3;fb++)
      #pragma unroll
      for(int i=0;i<4;i++){
        int row=wr*32+fa*16+rb*4+i;
        int band=wc*3+fb;
        int p=band>>2, cin=(band&3)*16+r16;
        float v = acc[fa][fb][i] + bias[p*512 + hh*64 + cin];
        unsigned short bv16 = f2b(v);
        qkB[(size_t)(bb*64+row)*1536 + p*512 + hh*64 + cin] = bv16;
        if(p==0)      tr_write(Qs,  row, cin, bv16);
        else if(p==1) tr_write(Ks2, row, cin, bv16);
        else          tr_write(Vt,  cin, row, bv16);
      }
  __syncthreads();

  int wr2=w>>2, wc2=w&3;
  f32x4 sa[2]={};
  #pragma unroll
  for(int h=0;h<2;h++){
    bf16x8 bfr = frag_read(Ks2, wc2*16+r16, h, kg);
    #pragma unroll
    for(int fa=0;fa<2;fa++){
      bf16x8 af = frag_read(Qs, wr2*32+fa*16+r16, h, kg);
      sa[fa]=__builtin_amdgcn_mfma_f32_16x16x32_bf16(af,bfr,sa[fa],0,0,0);
    }
  }
  #pragma unroll
  for(int fa=0;fa<2;fa++)
    #pragma unroll
    for(int i=0;i<4;i++){
      int row=wr2*32+fa*16+rb*4+i, col=wc2*16+r16;
      Sf[row*68+col] = (col<=row) ? sa[fa][i]*0.125f : -1e9f;
    }
  __syncthreads();

  {
    int srow=tid>>3, seg8=tid&7;
    float vals[8]; float mx=-3.4e38f;
    #pragma unroll
    for(int k2=0;k2<8;k2++){ vals[k2]=Sf[srow*68+seg8*8+k2]; mx=fmaxf(mx,vals[k2]); }
    mx=fmaxf(mx,__shfl_xor(mx,1)); mx=fmaxf(mx,__shfl_xor(mx,2)); mx=fmaxf(mx,__shfl_xor(mx,4));
    float sm=0;
    #pragma unroll
    for(int k2=0;k2<8;k2++){ vals[k2]=expf(vals[k2]-mx); sm+=vals[k2]; }
    sm+=__shfl_xor(sm,1); sm+=__shfl_xor(sm,2); sm+=__shfl_xor(sm,4);
    float inv=1.f/sm;
    short8 p0;
    #pragma unroll
    for(int k2=0;k2<8;k2++) p0[k2]=(short)f2b(vals[k2]*inv);
    __syncthreads();
    *(short8*)((char*)Pb + srow*128 + (((seg8)^(srow&7))<<4)) = p0;
    *(short8*)(ap + ((size_t)(bb*8+hh)*64 + srow)*64 + seg8*8) = p0;
  }
  __syncthreads();

  f32x4 oa[2]={};
  #pragma unroll
  for(int h=0;h<2;h++){
    bf16x8 bfr = frag_read(Vt, wc2*16+r16, h, kg);
    #pragma unroll
    for(int fa=0;fa<2;fa++){
      bf16x8 af = frag_read(Pb, wr2*32+fa*16+r16, h, kg);
      oa[fa]=__builtin_amdgcn_mfma_f32_16x16x32_bf16(af,bfr,oa[fa],0,0,0);
    }
  }
  #pragma unroll
  for(int fa=0;fa<2;fa++)
    #pragma unroll
    for(int i=0;i<4;i++){
      int row=wr2*32+fa*16+rb*4+i, col=wc2*16+r16;
      obuf[(size_t)(bb*64+row)*512 + hh*64 + col] = f2b(oa[fa][i]);
    }
}

// ============ fused do-GEMM + attention backward — 512 threads, group-parallel ============
__global__ __launch_bounds__(512) void k_do_attn(
    const unsigned short* __restrict__ dhBb, const unsigned short* __restrict__ projwB,
    const unsigned short* __restrict__ qkvB, const unsigned short* __restrict__ ap,
    unsigned short* __restrict__ dqkv)
{
  __shared__ __align__(16) short Asl[4*4096];
  __shared__ __align__(16) short Bsl2[4*4096];
  __shared__ __align__(16) short dOs[4096], Vs[4096], Kt[4096], Qt[4096], dOt[4096], Pt[4096], dsN[4096], dsT[4096];
  __shared__ float rsum[64][2];
  float* Pacc = (float*)Asl;
  int hh=blockIdx.x, bb=blockIdx.y;
  int tid=threadIdx.x, lane=tid&63, w=tid>>6;
  int wg=w>>2, wl=w&3;
  int wr=wl>>1, wc=wl&1, r16=lane&15, kg=lane>>4, rb=lane>>4;
  const unsigned short* qbase = qkvB + (size_t)bb*64*1536 + hh*64;
  const unsigned short* abase = ap + (size_t)(bb*8+hh)*64*64;

  {
    int row=tid>>3, gc=(tid&7)^(row&7);
    gll16(qbase + 1024 + (size_t)row*1536 + gc*8, (char*)Vs + tid*16);
  }
  {
    int row=tid>>3, c8=tid&7;
    short8 kreg=*(const short8*)(qbase+512+(size_t)row*1536+c8*8);
    short8 qreg=*(const short8*)(qbase+(size_t)row*1536+c8*8);
    short8 preg=*(const short8*)(abase+(size_t)row*64+c8*8);
    #pragma unroll
    for(int j=0;j<8;j++){
      int col=c8*8+j;
      tr_write(Kt, col, row, (unsigned short)kreg[j]);
      tr_write(Qt, col, row, (unsigned short)qreg[j]);
      tr_write(Pt, col, row, (unsigned short)preg[j]);
    }
  }

  const unsigned short* Bg = projwB + (size_t)(hh*64)*512;
  auto STAGE=[&](int t,int buf){
    int k0=(wg*4+t)*64;
    #pragma unroll
    for(int q=0;q<2;q++){
      int id=wl*128+q*64+lane, row=id>>3, gc=(id&7)^(row&7);
      gll16(dhBb + (size_t)(bb*64+row)*512 + k0 + gc*8, (char*)Asl + (wg*2+buf)*8192 + id*16);
      gll16(Bg + (size_t)row*512 + k0 + gc*8, (char*)Bsl2 + (wg*2+buf)*8192 + id*16);
    }
  };
  STAGE(0,0);
  f32x4 acc[2][2]={};
  for(int t=0;t<4;t++){
    int buf=t&1;
    STAGE(t+1<4?t+1:t, buf^1);
    asm volatile("s_waitcnt vmcnt(4)" ::: "memory");
    __builtin_amdgcn_sched_barrier(0);
    __builtin_amdgcn_s_barrier();
    __builtin_amdgcn_sched_barrier(0);
    const char* Ab=(const char*)Asl + (wg*2+buf)*8192;
    const char* Bb=(const char*)Bsl2 + (wg*2+buf)*8192;
    #pragma unroll
    for(int h=0;h<2;h++){
      bf16x8 af[2], bfr[2];
      #pragma unroll
      for(int f=0;f<2;f++){
        int rowa=wr*32+f*16+r16, ca=(h*4+kg)^(rowa&7);
        af[f]=__builtin_bit_cast(bf16x8, *(const short8*)(Ab + rowa*128 + ca*16));
        int rowb=wc*32+f*16+r16, cb=(h*4+kg)^(rowb&7);
        bfr[f]=__builtin_bit_cast(bf16x8, *(const short8*)(Bb + rowb*128 + cb*16));
      }
      #pragma unroll
      for(int fa=0;fa<2;fa++)
        #pragma unroll
        for(int fb=0;fb<2;fb++)
          acc[fa][fb]=__builtin_amdgcn_mfma_f32_16x16x32_bf16(af[fa],bfr[fb],acc[fa][fb],0,0,0);
    }
    asm volatile("s_waitcnt lgkmcnt(0)" ::: "memory");
    __builtin_amdgcn_sched_barrier(0);
    __builtin_amdgcn_s_barrier();
    __builtin_amdgcn_sched_barrier(0);
  }
  asm volatile("s_waitcnt vmcnt(0)" ::: "memory");
  __syncthreads();

  if(wg==1){
    #pragma unroll
    for(int fa=0;fa<2;fa++)
      #pragma unroll
      for(int fb=0;fb<2;fb++)
        #pragma unroll
        for(int i=0;i<4;i++){
          int row=wr*32+fa*16+rb*4+i, col=wc*32+fb*16+r16;
          Pacc[row*64+col]=acc[fa][fb][i];
        }
  }
  __syncthreads();
  if(wg==0){
    #pragma unroll
    for(int fa=0;fa<2;fa++)
      #pragma unroll
      for(int fb=0;fb<2;fb++)
        #pragma unroll
        for(int i=0;i<4;i++){
          int row=wr*32+fa*16+rb*4+i, col=wc*32+fb*16+r16;
          unsigned short db = f2b(acc[fa][fb][i] + Pacc[row*64+col]);
          tr_write(dOs, row, col, db);
          tr_write(dOt, col, row, db);
        }
  }
  __syncthreads();

  f32x4 da[2][2]={};
  float pv[2][2][4];
  if(wg==0){
    #pragma unroll
    for(int h=0;h<2;h++){
      bf16x8 af[2], bfr[2];
      #pragma unroll
      for(int f=0;f<2;f++){ af[f]=frag_read(dOs, wr*32+f*16+r16, h, kg); bfr[f]=frag_read(Vs, wc*32+f*16+r16, h, kg); }
      #pragma unroll
      for(int fa=0;fa<2;fa++)
        #pragma unroll
        for(int fb=0;fb<2;fb++)
          da[fa][fb]=__builtin_amdgcn_mfma_f32_16x16x32_bf16(af[fa],bfr[fb],da[fa][fb],0,0,0);
    }
    float part[2][4]={};
    #pragma unroll
    for(int fa=0;fa<2;fa++)
      #pragma unroll
      for(int i=0;i<4;i++){
        #pragma unroll
        for(int fb=0;fb<2;fb++){
          int row=wr*32+fa*16+rb*4+i, col=wc*32+fb*16+r16;
          float p = b2f(*(const unsigned short*)((const char*)Pt + col*128 + (((row>>3)^(col&7))<<4) + (row&7)*2));
          pv[fa][fb][i]=p;
          part[fa][i] += p*da[fa][fb][i];
        }
        float s=part[fa][i];
        #pragma unroll
        for(int msk=1;msk<16;msk<<=1) s += __shfl_xor(s,msk);
        if(r16==0) rsum[wr*32+fa*16+rb*4+i][wc]=s;
      }
  } else {
    f32x4 dvv[2][2]={};
    #pragma unroll
    for(int h=0;h<2;h++){
      bf16x8 af[2], bfr[2];
      #pragma unroll
      for(int f=0;f<2;f++){ af[f]=frag_read(Pt, wr*32+f*16+r16, h, kg); bfr[f]=frag_read(dOt, wc*32+f*16+r16, h, kg); }
      #pragma unroll
      for(int fa=0;fa<2;fa++)
        #pragma unroll
        for(int fb=0;fb<2;fb++)
          dvv[fa][fb]=__builtin_amdgcn_mfma_f32_16x16x32_bf16(af[fa],bfr[fb],dvv[fa][fb],0,0,0);
    }
    #pragma unroll
    for(int fa=0;fa<2;fa++)
      #pragma unroll
      for(int fb=0;fb<2;fb++)
        #pragma unroll
        for(int i=0;i<4;i++){
          int row=wr*32+fa*16+rb*4+i, col=wc*32+fb*16+r16;
          dqkv[(size_t)(bb*64+row)*1536 + hh*64 + 1024 + col] = f2b(dvv[fa][fb][i]);
        }
  }
  __syncthreads();

  if(wg==0){
    #pragma unroll
    for(int fa=0;fa<2;fa++)
      #pragma unroll
      for(int fb=0;fb<2;fb++)
        #pragma unroll
        for(int i=0;i<4;i++){
          int row=wr*32+fa*16+rb*4+i, col=wc*32+fb*16+r16;
          float rt = rsum[row][0]+rsum[row][1];
          float ds = pv[fa][fb][i]*(da[fa][fb][i]-rt)*0.125f;
          unsigned short db = f2b(ds);
          tr_write(dsN, row, col, db);
          tr_write(dsT, col, row, db);
        }
  }
  __syncthreads();

  {
    const short* Am = wg ? dsT : dsN;
    const short* Bm = wg ? Qt  : Kt;
    int ofs = wg ? 512 : 0;
    f32x4 a2[2][2]={};
    #pragma unroll
    for(int h=0;h<2;h++){
      bf16x8 af[2], bfr[2];
      #pragma unroll
      for(int f=0;f<2;f++){ af[f]=frag_read(Am, wr*32+f*16+r16, h, kg); bfr[f]=frag_read(Bm, wc*32+f*16+r16, h, kg); }
      #pragma unroll
      for(int fa=0;fa<2;fa++)
        #pragma unroll
        for(int fb=0;fb<2;fb++)
          a2[fa][fb]=__builtin_amdgcn_mfma_f32_16x16x32_bf16(af[fa],bfr[fb],a2[fa][fb],0,0,0);
    }
    #pragma unroll
    for(int fa=0;fa<2;fa++)
      #pragma unroll
      for(int fb=0;fb<2;fb++)
        #pragma unroll
        for(int i=0;i<4;i++){
          int row=wr*32+fa*16+rb*4+i, col=wc*32+fb*16+r16;
          dqkv[(size_t)(bb*64+row)*1536 + hh*64 + ofs + col] = f2b(a2[fa][fb][i]);
        }
  }
}

// ============ fused CE stats + dlogits -> bf16 (1024 threads, wave reductions) ============
__global__ __launch_bounds__(1024) void k_ce_dlog(const float* __restrict__ out, const int* __restrict__ x,
    unsigned short* __restrict__ dlog, int chunk)
{
  __shared__ unsigned short eb[32000];
  __shared__ float red[16];
  int n = blockIdx.x, tid = threadIdx.x;
  int lane = tid&63, w = tid>>6;
  int b = n>>6, t = n&63;
  int R = b*256 + chunk*64 + t;
  int tgt = x[b*257 + chunk*64 + t + 1];
  const float* row = out + (size_t)R*32000;

  float mx = -3.4e38f;
  for(int v=tid; v<32000; v+=1024){ float l=row[v]; mx=fmaxf(mx,l); eb[v]=f2b(l); }
  #pragma unroll
  for(int off=32;off;off>>=1) mx = fmaxf(mx, __shfl_xor(mx,off));
  if(lane==0) red[w]=mx;
  __syncthreads();
  float m = red[0];
  #pragma unroll
  for(int i=1;i<16;i++) m = fmaxf(m, red[i]);
  __syncthreads();

  float s=0;
  for(int v=tid; v<32000; v+=1024){ float e = expf(b2f(eb[v])-m); s+=e; eb[v]=f2b(e); }
  #pragma unroll
  for(int off=32;off;off>>=1) s += __shfl_xor(s,off);
  if(lane==0) red[w]=s;
  __syncthreads();
  float tot = 0.f;
  #pragma unroll
  for(int i=0;i<16;i++) tot += red[i];
  float iz = 1.f/tot * (1.f/256.f);

  unsigned short* dr = dlog + (size_t)n*32000;
  for(int v=tid; v<32000; v+=1024){
    float a = b2f(eb[v])*iz;
    if(v==tgt) a -= (1.f/256.f);
    dr[v] = f2b(a);
  }
}

extern "C" void kernel_launch(void* const* d_in, const int* in_sizes, int n_in,
                              void* d_out, int out_size, void* d_ws, size_t ws_size,
                              hipStream_t stream)
{
  const int*   x      = (const int*)d_in[0];
  const float* embed  = (const float*)d_in[1];
  const float* pos    = (const float*)d_in[2];
  const float* ln1_g  = (const float*)d_in[3];
  const float* ln1_b  = (const float*)d_in[4];
  const float* qkv_w  = (const float*)d_in[5];
  const float* qkv_b  = (const float*)d_in[6];
  const float* proj_w = (const float*)d_in[7];
  const float* proj_b = (const float*)d_in[8];
  const float* ln2_g  = (const float*)d_in[9];
  const float* ln2_b  = (const float*)d_in[10];
  const float* mlp_w1 = (const float*)d_in[11];
  const float* mlp_b1 = (const float*)d_in[12];
  const float* mlp_w2 = (const float*)d_in[13];
  const float* mlp_b2 = (const float*)d_in[14];
  const float* lnf_g  = (const float*)d_in[15];
  const float* lnf_b  = (const float*)d_in[16];
  const float* head_w = (const float*)d_in[17];
  const float* head_b = (const float*)d_in[18];
  float* out = (float*)d_out;

  char* base = (char*)d_ws;
  size_t off = 0;
  auto AB = [&](size_t bytes)->char*{ char* p = base + off; off += (bytes + 255) & ~(size_t)255; return p; };
  // fp32
  float* W1c  = (float*)AB(16777216);
  float* W2c  = (float*)AB(16777216);
  float* B1c  = (float*)AB(32768);
  float* B2c  = (float*)AB(8192);
  float* hin  = (float*)AB(5*524288);
  float* h1s  = (float*)AB(4*524288);
  float* z1s  = (float*)AB(4*2097152);
  float* dhA  = (float*)AB(524288);
  float* dhB  = (float*)AB(524288);
  float* dxn  = (float*)AB(524288);
  float* dpart= (float*)AB(50*524288);
  float* stats= (float*)AB(4*9*2*256*4);
  // bf16
  unsigned short* qkvwB = (unsigned short*)AB(6291456);
  unsigned short* qkvwT = (unsigned short*)AB(6291456);
  unsigned short* projwB= (unsigned short*)AB(2097152);
  unsigned short* projwT= (unsigned short*)AB(2097152);
  unsigned short* headwB= (unsigned short*)AB(32768000);
  unsigned short* headwT= (unsigned short*)AB(32768000);
  unsigned short* W1b   = (unsigned short*)AB(8388608);
  unsigned short* W1t   = (unsigned short*)AB(8388608);
  unsigned short* W2b   = (unsigned short*)AB(8388608);
  unsigned short* W2t   = (unsigned short*)AB(8388608);
  unsigned short* z1gs  = (unsigned short*)AB(4194304);
  unsigned short* qkBs  = (unsigned short*)AB(4*786432);
  unsigned short* apBs  = (unsigned short*)AB(4*262144);
  unsigned short* obufB = (unsigned short*)AB(262144);
  unsigned short* dlogB = (unsigned short*)AB(16384000);
  unsigned short* dhbB  = (unsigned short*)AB(5*262144);
  unsigned short* dhBb  = (unsigned short*)AB(262144);
  unsigned short* dz1bs = (unsigned short*)AB(4*1048576);
  unsigned short* dqkvB = (unsigned short*)AB(786432);

  auto SS1 = [&](int c, int s)->float*{ return stats + ((size_t)(c*9+s)*2)*256; };
  auto SS2 = [&](int c, int s)->float*{ return stats + ((size_t)(c*9+s)*2)*256 + 256; };

  k_setup<<<72,256,0,stream>>>(stats, B1c, mlp_b1, B2c, mlp_b2);
  k_cvt_t<<<dim3(24,8,4),256,0,stream>>>(qkv_w, qkvwT, qkvwB, nullptr, 512, 1536);
  k_cvt_t<<<dim3(8,8,4),256,0,stream>>>(proj_w, projwT, projwB, nullptr, 512, 512);
  k_cvt_t<<<dim3(500,8,1),256,0,stream>>>(head_w, headwT, headwB, nullptr, 512, 32000);
  k_cvt_t<<<dim3(32,8,4),256,0,stream>>>(mlp_w1, W1t, W1b, W1c, 512, 2048);
  k_cvt_t<<<dim3(8,32,4),256,0,stream>>>(mlp_w2, W2t, W2b, W2c, 2048, 512);

  for(int c=0;c<4;c++){
    // ---------------- forward ----------------
    k_embed<<<256,256,0,stream>>>(x, embed, pos, hin, SS1(c,0), SS2(c,0), c);
    for(int i=0;i<4;i++){
      float* h0 = hin + (size_t)i*131072;
      float* h2 = hin + (size_t)(i+1)*131072;
      float* h1 = h1s + (size_t)i*131072;
      float* z1 = z1s + (size_t)i*524288;
      unsigned short* z1g = z1gs + (size_t)i*524288;
      unsigned short* qkB = qkBs + (size_t)i*393216;
      unsigned short* apB = apBs + (size_t)i*131072;
      k_qkv_attn<<<dim3(8,4),512,0,stream>>>(h0, SS1(c,i), SS2(c,i), ln1_g+i*512, ln1_b+i*512,
          qkvwT+(size_t)i*786432, qkv_b+i*1536, qkB, obufB, apB);
      k_nt32<0,1><<<dim3(16,8),256,0,stream>>>(obufB, nullptr, nullptr, nullptr, nullptr, nullptr,
          projwT+(size_t)i*262144, proj_b+i*512, h0, nullptr,
          h1, nullptr, SS1(c,5+i), SS2(c,5+i), 256,512,512, 8, 0);
      k_nt32<1,0><<<dim3(64,8),256,0,stream>>>(nullptr, h1, SS1(c,5+i), SS2(c,5+i), ln2_g+i*512, ln2_b+i*512,
          W1t+(size_t)i*1048576, B1c+i*2048, nullptr, nullptr,
          z1, z1g, nullptr, nullptr, 256,2048,512, 8, 1);
      k_nt32<0,1><<<dim3(16,8),256,0,stream>>>(z1g, nullptr, nullptr, nullptr, nullptr, nullptr,
          W2t+(size_t)i*1048576, B2c+i*512, h1, nullptr,
          h2, nullptr, SS1(c,i+1), SS2(c,i+1), 256,512,2048, 32, 0);
    }
    k_nt<128,1,0><<<dim3(250,2),256,0,stream>>>(nullptr, hin+4*131072, SS1(c,4), SS2(c,4), lnf_g, lnf_b,
        headwT, head_b, nullptr, nullptr,
        out, nullptr, nullptr, nullptr, 256,32000,512, 8, 0, c);

    // ---------------- backward ----------------
    k_ce_dlog<<<256,1024,0,stream>>>(out, x, dlogB, c);
    k_nt<128,0,0><<<dim3(4,2,50),256,0,stream>>>(dlogB, nullptr, nullptr, nullptr, nullptr, nullptr,
        headwB, nullptr, nullptr, nullptr,
        dpart, nullptr, nullptr, nullptr, 256,512,32000, 10, 0, -1);
    k_ln_bwd<<<256,256,0,stream>>>(nullptr, dpart, 50, hin+4*131072, lnf_g, SS1(c,4), SS2(c,4),
        nullptr, dhA, dhbB + 3*131072);
    for(int i=3;i>=1;i--){
      float* h0 = hin + (size_t)i*131072;
      float* h1 = h1s + (size_t)i*131072;
      float* z1 = z1s + (size_t)i*524288;
      unsigned short* qkB = qkBs + (size_t)i*393216;
      unsigned short* apB = apBs + (size_t)i*131072;
      k_nt32<0,0><<<dim3(64,8),256,0,stream>>>(dhbB + (size_t)i*131072, nullptr, nullptr, nullptr, nullptr, nullptr,
          W2b+(size_t)i*1048576, nullptr, nullptr, z1,
          nullptr, dz1bs + (size_t)i*524288, nullptr, nullptr, 256,2048,512, 8, 0);
      k_nt32<0,0><<<dim3(16,8),256,0,stream>>>(dz1bs + (size_t)i*524288, nullptr, nullptr, nullptr, nullptr, nullptr,
          W1b+(size_t)i*1048576, nullptr, nullptr, nullptr,
          dxn, nullptr, nullptr, nullptr, 256,512,2048, 32, 0);
      k_ln_bwd<<<256,256,0,stream>>>(dxn, nullptr, 0, h1, ln2_g+i*512, SS1(c,5+i), SS2(c,5+i),
          dhA, dhB, dhBb);
      k_do_attn<<<dim3(8,4),512,0,stream>>>(dhBb, projwB+(size_t)i*262144, qkB, apB, dqkvB);
      k_nt32<0,0><<<dim3(16,8),256,0,stream>>>(dqkvB, nullptr, nullptr, nullptr, nullptr, nullptr,
          qkvwB+(size_t)i*786432, nullptr, nullptr, nullptr,
          dxn, nullptr, nullptr, nullptr, 256,512,1536, 24, 0);
      k_ln_bwd<<<256,256,0,stream>>>(dxn, nullptr, 0, h0, ln1_g+i*512, SS1(c,i), SS2(c,i),
          dhB, dhA, dhbB + (size_t)(i-1)*131072);
    }
    // i == 0: only dz1 is live (feeds W1/W2/b1/b2 updates); the rest of the
    // backward chain propagates into non-trainable params and is dead.
    k_nt32<0,0><<<dim3(64,8),256,0,stream>>>(dhbB, nullptr, nullptr, nullptr, nullptr, nullptr,
        W2b, nullptr, nullptr, z1s,
        nullptr, dz1bs, nullptr, nullptr, 256,2048,512, 8, 0);
    k_sgd_all<<<2048,256,0,stream>>>(z1gs, dhbB, dz1bs, h1s, stats, c,
        W1c, W1b, W1t, B1c, W2c, W2b, W2t, B2c, ln2_g, ln2_b);
  }
}

// Round 12
// 2168.109 us; speedup vs baseline: 1.1907x; 1.0077x over previous
//
#include <hip/hip_runtime.h>
#include <cstddef>

#define LRATE 3e-4f

typedef short short8 __attribute__((ext_vector_type(8)));
typedef float f32x4 __attribute__((ext_vector_type(4)));
typedef __bf16 bf16x8 __attribute__((ext_vector_type(8)));

__device__ __forceinline__ unsigned short f2b(float f){
  unsigned u = __builtin_bit_cast(unsigned, f);
  unsigned r = (u + 0x7fffu + ((u>>16)&1u)) >> 16;
  return (unsigned short)r;
}
__device__ __forceinline__ float b2f(unsigned short s){
  unsigned u = ((unsigned)s)<<16;
  return __builtin_bit_cast(float, u);
}
__device__ __forceinline__ float gelu_f(float x){
  float u = 0.7978845608028654f*(x + 0.044715f*x*x*x);
  float t = tanhf(u);
  return 0.5f*x*(1.f+t);
}
__device__ __forceinline__ float gelu_df(float x){
  float x2 = x*x;
  float u = 0.7978845608028654f*(x + 0.044715f*x*x2);
  float t = tanhf(u);
  return 0.5f*(1.f+t) + 0.5f*x*(1.f-t*t)*0.7978845608028654f*(1.f+0.134145f*x2);
}
__device__ __forceinline__ void gll16(const void* g, void* l){
  __builtin_amdgcn_global_load_lds(
      (const __attribute__((address_space(1))) unsigned int*)(g),
      (__attribute__((address_space(3))) unsigned int*)(l), 16, 0, 0);
}
__device__ __forceinline__ bf16x8 frag_read(const short* base, int row, int h, int kg){
  int c = (h*4+kg) ^ (row&7);
  return __builtin_bit_cast(bf16x8, *(const short8*)((const char*)base + row*128 + c*16));
}
__device__ __forceinline__ void tr_write(short* base, int nrow, int k, unsigned short v){
  *(short*)((char*)base + nrow*128 + (((k>>3)^(nrow&7))<<4) + (k&7)*2) = (short)v;
}

// ============ TILE=128 NT bf16 MFMA GEMM, 2-phase pipelined (head fwd/bwd only) ============
template<int TILE, int LNA, int STATS>
__global__ __launch_bounds__(256) void k_nt(
    const unsigned short* __restrict__ Ag,
    const float* __restrict__ Af, const float* __restrict__ aS1, const float* __restrict__ aS2,
    const float* __restrict__ lng, const float* __restrict__ lnb,
    const unsigned short* __restrict__ Bg,
    const float* __restrict__ bias, const float* __restrict__ resid, const float* __restrict__ zsrc,
    float* __restrict__ outf, unsigned short* __restrict__ outb,
    float* __restrict__ oS1, float* __restrict__ oS2,
    int M, int N, int K, int k_iters, int gelu_b, int remap_c)
{
  constexpr int F = TILE/32;
  constexpr int CH = TILE/32;
  __shared__ __align__(16) short Asm[2*TILE*64];
  __shared__ __align__(16) short Bsm[2*TILE*64];
  int tid=threadIdx.x, lane=tid&63, w=tid>>6;
  int wr=w>>1, wc=w&1, r16=lane&15, kg=lane>>4;
  int bn=blockIdx.x*TILE, bm=blockIdx.y*TILE;
  int kbase = blockIdx.z*k_iters*64;
  f32x4 acc[F][F]={};

  int ids[CH], rows[CH];
  float mA[CH], rA[CH];
  #pragma unroll
  for(int q=0;q<CH;q++){ ids[q]=w*(TILE*2)+q*64+lane; rows[q]=ids[q]>>3; }
  if constexpr(LNA){
    #pragma unroll
    for(int q=0;q<CH;q++){
      float s1=aS1[bm+rows[q]], s2=aS2[bm+rows[q]];
      float mm=s1*(1.f/512.f);
      mA[q]=mm; rA[q]=rsqrtf(s2*(1.f/512.f)-mm*mm+1e-5f);
    }
  }

  auto STAGE=[&](int t,int buf){
    int k0 = kbase + t*64;
    short* Ad = Asm + buf*TILE*64;
    short* Bd = Bsm + buf*TILE*64;
    if constexpr(LNA==0){
      #pragma unroll
      for(int q=0;q<CH;q++){
        int gc=(ids[q]&7)^(rows[q]&7);
        gll16(Ag + (size_t)(bm+rows[q])*K + k0 + gc*8, (char*)Ad + ids[q]*16);
      }
    } else {
      #pragma unroll
      for(int q=0;q<CH;q++){
        int gc=(ids[q]&7)^(rows[q]&7);
        const float* src = Af + (size_t)(bm+rows[q])*K + k0 + gc*8;
        float4 v0=*(const float4*)src, v1=*(const float4*)(src+4);
        const float* gp=lng+k0+gc*8; const float* bp=lnb+k0+gc*8;
        float4 g0=*(const float4*)gp, g1=*(const float4*)(gp+4);
        float4 c0=*(const float4*)bp, c1=*(const float4*)(bp+4);
        float mm=mA[q], rr=rA[q];
        short8 o;
        o[0]=(short)f2b((v0.x-mm)*rr*g0.x+c0.x);
        o[1]=(short)f2b((v0.y-mm)*rr*g0.y+c0.y);
        o[2]=(short)f2b((v0.z-mm)*rr*g0.z+c0.z);
        o[3]=(short)f2b((v0.w-mm)*rr*g0.w+c0.w);
        o[4]=(short)f2b((v1.x-mm)*rr*g1.x+c1.x);
        o[5]=(short)f2b((v1.y-mm)*rr*g1.y+c1.y);
        o[6]=(short)f2b((v1.z-mm)*rr*g1.z+c1.z);
        o[7]=(short)f2b((v1.w-mm)*rr*g1.w+c1.w);
        *(short8*)((char*)Ad + ids[q]*16) = o;
      }
    }
    #pragma unroll
    for(int q=0;q<CH;q++){
      int gc=(ids[q]&7)^(rows[q]&7);
      gll16(Bg + (size_t)(bn+rows[q])*K + k0 + gc*8, (char*)Bd + ids[q]*16);
    }
  };

  STAGE(0,0);
  for(int t=0;t<k_iters;++t){
    int buf=t&1;
    STAGE(t+1<k_iters?t+1:t, buf^1);
    asm volatile("" ::: "memory");
    constexpr int VMC = LNA ? (TILE/32) : (TILE/16);
    if constexpr(VMC==2)      asm volatile("s_waitcnt vmcnt(2)" ::: "memory");
    else if constexpr(VMC==4) asm volatile("s_waitcnt vmcnt(4)" ::: "memory");
    else                      asm volatile("s_waitcnt vmcnt(8)" ::: "memory");
    __builtin_amdgcn_sched_barrier(0);
    __builtin_amdgcn_s_barrier();
    asm volatile("" ::: "memory");
    const char* Ab=(const char*)(Asm+buf*TILE*64);
    const char* Bb=(const char*)(Bsm+buf*TILE*64);
    #pragma unroll
    for(int h=0;h<2;h++){
      bf16x8 af[F], bfr[F];
      #pragma unroll
      for(int fa=0;fa<F;fa++){
        int row=wr*(TILE/2)+fa*16+r16;
        int c=(h*4+kg)^(row&7);
        af[fa]=__builtin_bit_cast(bf16x8, *(const short8*)(Ab + row*128 + c*16));
      }
      #pragma unroll
      for(int fb=0;fb<F;fb++){
        int row=wc*(TILE/2)+fb*16+r16;
        int c=(h*4+kg)^(row&7);
        bfr[fb]=__builtin_bit_cast(bf16x8, *(const short8*)(Bb + row*128 + c*16));
      }
      #pragma unroll
      for(int fa=0;fa<F;fa++)
        #pragma unroll
        for(int fb=0;fb<F;fb++)
          acc[fa][fb]=__builtin_amdgcn_mfma_f32_16x16x32_bf16(af[fa],bfr[fb],acc[fa][fb],0,0,0);
    }
    asm volatile("s_waitcnt lgkmcnt(0)" ::: "memory");
    __builtin_amdgcn_sched_barrier(0);
    __builtin_amdgcn_s_barrier();
    asm volatile("" ::: "memory");
  }
  asm volatile("s_waitcnt vmcnt(0)" ::: "memory");

  int rb = lane>>4;
  float st1[F][4]={}, st2[F][4]={};
  #pragma unroll
  for(int fa=0; fa<F; fa++){
    #pragma unroll
    for(int fb=0; fb<F; fb++){
      f32x4 av = acc[fa][fb];
      #pragma unroll
      for(int i=0;i<4;i++){
        int m = bm + wr*(TILE/2) + fa*16 + rb*4 + i;
        int n = bn + wc*(TILE/2) + fb*16 + r16;
        float v = av[i];
        if(bias) v += bias[n];
        if(resid) v += resid[(size_t)m*N + n];
        if(zsrc) v *= gelu_df(zsrc[(size_t)m*N + n]);
        if constexpr(STATS){ st1[fa][i] += v; st2[fa][i] += v*v; }
        int mo = (remap_c>=0)? ((m>>6)*256 + remap_c*64 + (m&63)) : m;
        if(outf) outf[(size_t)blockIdx.z*M*N + (size_t)mo*N + n] = v;
        if(outb) outb[(size_t)mo*N + n] = f2b(gelu_b ? gelu_f(v) : v);
      }
    }
  }
  if constexpr(STATS){
    #pragma unroll
    for(int fa=0; fa<F; fa++){
      #pragma unroll
      for(int i=0;i<4;i++){
        float s1 = st1[fa][i], s2 = st2[fa][i];
        #pragma unroll
        for(int msk=1; msk<16; msk<<=1){ s1 += __shfl_xor(s1,msk); s2 += __shfl_xor(s2,msk); }
        if(r16==0){
          int m = bm + wr*(TILE/2) + fa*16 + rb*4 + i;
          atomicAdd(&oS1[m], s1);
          atomicAdd(&oS2[m], s2);
        }
      }
    }
  }
}

// ============ TILE=32 NT GEMM, 8-slot rolling prefetch (PF=6) ============
// zsrc fp32 or zsrcb bf16 (gelu-bwd); outb (opt gelu) + outb2 (raw bf16) outputs.
template<int LNA, int STATS>
__global__ __launch_bounds__(256) void k_nt32(
    const unsigned short* __restrict__ Ag,
    const float* __restrict__ Af, const float* __restrict__ aS1, const float* __restrict__ aS2,
    const float* __restrict__ lng, const float* __restrict__ lnb,
    const unsigned short* __restrict__ Bg,
    const float* __restrict__ bias, const float* __restrict__ resid,
    const float* __restrict__ zsrc, const unsigned short* __restrict__ zsrcb,
    float* __restrict__ outf, unsigned short* __restrict__ outb, unsigned short* __restrict__ outb2,
    float* __restrict__ oS1, float* __restrict__ oS2,
    int M, int N, int K, int k_iters, int gelu_b)
{
  __shared__ __align__(16) short Asl[8*2048];
  __shared__ __align__(16) short Bsl[8*2048];
  int tid=threadIdx.x, lane=tid&63, w=tid>>6;
  int wr=w>>1, wc=w&1, r16=lane&15, kg=lane>>4;
  int bn=blockIdx.x*32, bm=blockIdx.y*32;
  int row=tid>>3, s8=tid&7, gc=s8^(row&7);
  f32x4 acc={0.f,0.f,0.f,0.f};

  auto ISSUE_A=[&](int t,int slot){
    gll16(Ag + (size_t)(bm+row)*K + t*64 + gc*8, (char*)Asl + slot*4096 + tid*16);
  };
  auto ISSUE_B=[&](int t,int slot){
    gll16(Bg + (size_t)(bn+row)*K + t*64 + gc*8, (char*)Bsl + slot*4096 + tid*16);
  };

  if constexpr(LNA){
    float mm, rr;
    { float a=aS1[bm+row], b=aS2[bm+row]; mm=a*(1.f/512.f); rr=rsqrtf(b*(1.f/512.f)-mm*mm+1e-5f); }
    for(int t=0;t<k_iters;t++){
      const float* src = Af + (size_t)(bm+row)*K + t*64 + gc*8;
      float4 v0=*(const float4*)src, v1=*(const float4*)(src+4);
      const float* gp=lng+t*64+gc*8; const float* bp=lnb+t*64+gc*8;
      float4 g0=*(const float4*)gp, g1=*(const float4*)(gp+4);
      float4 c0=*(const float4*)bp, c1=*(const float4*)(bp+4);
      short8 o;
      o[0]=(short)f2b((v0.x-mm)*rr*g0.x+c0.x);
      o[1]=(short)f2b((v0.y-mm)*rr*g0.y+c0.y);
      o[2]=(short)f2b((v0.z-mm)*rr*g0.z+c0.z);
      o[3]=(short)f2b((v0.w-mm)*rr*g0.w+c0.w);
      o[4]=(short)f2b((v1.x-mm)*rr*g1.x+c1.x);
      o[5]=(short)f2b((v1.y-mm)*rr*g1.y+c1.y);
      o[6]=(short)f2b((v1.z-mm)*rr*g1.z+c1.z);
      o[7]=(short)f2b((v1.w-mm)*rr*g1.w+c1.w);
      *(short8*)((char*)Asl + t*4096 + tid*16) = o;
    }
  }

  #pragma unroll
  for(int s=0;s<6;s++){
    if constexpr(LNA==0) ISSUE_A(s, s);
    ISSUE_B(s, s);
  }
  if constexpr(LNA){
    asm volatile("s_waitcnt lgkmcnt(0)" ::: "memory");
    __builtin_amdgcn_sched_barrier(0);
    __builtin_amdgcn_s_barrier();
  }

  for(int t=0;t<k_iters;++t){
    int tt = (t+6<k_iters)? t+6 : k_iters-1;
    int slot=(t+6)&7;
    if constexpr(LNA==0) ISSUE_A(tt, slot);
    ISSUE_B(tt, slot);
    if constexpr(LNA==0) asm volatile("s_waitcnt vmcnt(12)" ::: "memory");
    else                 asm volatile("s_waitcnt vmcnt(6)" ::: "memory");
    __builtin_amdgcn_sched_barrier(0);
    __builtin_amdgcn_s_barrier();
    __builtin_amdgcn_sched_barrier(0);
    const char* Ab = LNA ? (const char*)Asl + t*4096 : (const char*)Asl + (t&7)*4096;
    const char* Bb = (const char*)Bsl + (t&7)*4096;
    #pragma unroll
    for(int h=0;h<2;h++){
      int rowa=wr*16+r16, ca=(h*4+kg)^(rowa&7);
      bf16x8 a=__builtin_bit_cast(bf16x8, *(const short8*)(Ab + rowa*128 + ca*16));
      int rowb=wc*16+r16, cb=(h*4+kg)^(rowb&7);
      bf16x8 b=__builtin_bit_cast(bf16x8, *(const short8*)(Bb + rowb*128 + cb*16));
      acc=__builtin_amdgcn_mfma_f32_16x16x32_bf16(a,b,acc,0,0,0);
    }
    asm volatile("s_waitcnt lgkmcnt(0)" ::: "memory");
    __builtin_amdgcn_sched_barrier(0);
  }
  asm volatile("s_waitcnt vmcnt(0)" ::: "memory");

  int rb=lane>>4;
  float st1[4]={}, st2[4]={};
  #pragma unroll
  for(int i=0;i<4;i++){
    int m = bm + wr*16 + rb*4 + i;
    int n = bn + wc*16 + r16;
    float v = acc[i];
    if(bias) v += bias[n];
    if(resid) v += resid[(size_t)m*N + n];
    if(zsrc) v *= gelu_df(zsrc[(size_t)m*N + n]);
    if(zsrcb) v *= gelu_df(b2f(zsrcb[(size_t)m*N + n]));
    if constexpr(STATS){ st1[i]=v; st2[i]=v*v; }
    if(outf) outf[(size_t)m*N + n] = v;
    if(outb) outb[(size_t)m*N + n] = f2b(gelu_b ? gelu_f(v) : v);
    if(outb2) outb2[(size_t)m*N + n] = f2b(v);
  }
  if constexpr(STATS){
    #pragma unroll
    for(int i=0;i<4;i++){
      float s1=st1[i], s2=st2[i];
      #pragma unroll
      for(int msk=1;msk<16;msk<<=1){ s1+=__shfl_xor(s1,msk); s2+=__shfl_xor(s2,msk); }
      if(r16==0){
        int m = bm + wr*16 + rb*4 + i;
        atomicAdd(&oS1[m], s1);
        atomicAdd(&oS2[m], s2);
      }
    }
  }
}

// ============ TN wgrad + SGD body ============
template<int LNA>
__device__ __forceinline__ void sgd_body(
    const unsigned short* __restrict__ Ag,
    const float* __restrict__ Af, const float* __restrict__ aS1, const float* __restrict__ aS2,
    const float* __restrict__ lng, const float* __restrict__ lnb,
    const unsigned short* __restrict__ Bg,
    float* __restrict__ Wf, unsigned short* __restrict__ Wb, unsigned short* __restrict__ Wt,
    float* __restrict__ bv, int M, int N, int bm, int bn,
    short* Asm, short* Bsm, short* Tsm)
{
  int tid = threadIdx.x;
  f32x4 acc00={},acc01={},acc10={},acc11={};
  int lane = tid&63, w = tid>>6, wr = w>>1, wc = w&1;
  int r16 = lane&15, kg = lane>>4;
  float gv[8], bvv[8];
  if constexpr(LNA){
    int ms=(tid&7)*8;
    #pragma unroll
    for(int j=0;j<8;j++){ gv[j]=lng[bm+ms+j]; bvv[j]=lnb[bm+ms+j]; }
  }
  float csum = 0.f;
  int docs = (bv && bm==0 && tid<64);
  for(int k0=0; k0<256; k0+=32){
    if constexpr(LNA==0){
      int kk = tid>>3, ms=(tid&7)*8;
      short8 v = *(const short8*)(Ag + (size_t)(k0+kk)*M + bm + ms);
      #pragma unroll
      for(int j=0;j<8;j++){ int row=ms+j; Asm[row*40 + (((kk>>3)^((row>>3)&3))<<3) + (kk&7)] = v[j]; }
    } else {
      int kk = tid>>3, ms=(tid&7)*8;
      int token = k0+kk;
      float s1=aS1[token], s2=aS2[token];
      float mm=s1*(1.f/512.f);
      float rr=rsqrtf(s2*(1.f/512.f)-mm*mm+1e-5f);
      const float* src = Af + (size_t)token*M + bm + ms;
      float4 v0=*(const float4*)src, v1=*(const float4*)(src+4);
      float vals[8]={v0.x,v0.y,v0.z,v0.w,v1.x,v1.y,v1.z,v1.w};
      #pragma unroll
      for(int j=0;j<8;j++){
        int row=ms+j;
        Asm[row*40 + (((kk>>3)^((row>>3)&3))<<3) + (kk&7)] = (short)f2b((vals[j]-mm)*rr*gv[j]+bvv[j]);
      }
    }
    { int kk = tid>>3, ns=(tid&7)*8;
      short8 v = *(const short8*)(Bg + (size_t)(k0+kk)*N + bn + ns);
      #pragma unroll
      for(int j=0;j<8;j++){ int row=ns+j; Bsm[row*40 + (((kk>>3)^((row>>3)&3))<<3) + (kk&7)] = v[j]; } }
    __syncthreads();
    if(docs){
      #pragma unroll
      for(int kk2=0;kk2<32;kk2++)
        csum += b2f((unsigned short)Bsm[tid*40 + (((kk2>>3)^((tid>>3)&3))<<3) + (kk2&7)]);
    }
    int ra0 = wr*32 + r16, ra1 = ra0+16, rb0 = wc*32 + r16, rb1 = rb0+16;
    bf16x8 a0 = __builtin_bit_cast(bf16x8, *(const short8*)(Asm + ra0*40 + ((kg ^ ((ra0>>3)&3))<<3)));
    bf16x8 a1 = __builtin_bit_cast(bf16x8, *(const short8*)(Asm + ra1*40 + ((kg ^ ((ra1>>3)&3))<<3)));
    bf16x8 b0 = __builtin_bit_cast(bf16x8, *(const short8*)(Bsm + rb0*40 + ((kg ^ ((rb0>>3)&3))<<3)));
    bf16x8 b1 = __builtin_bit_cast(bf16x8, *(const short8*)(Bsm + rb1*40 + ((kg ^ ((rb1>>3)&3))<<3)));
    acc00 = __builtin_amdgcn_mfma_f32_16x16x32_bf16(a0, b0, acc00, 0,0,0);
    acc01 = __builtin_amdgcn_mfma_f32_16x16x32_bf16(a0, b1, acc01, 0,0,0);
    acc10 = __builtin_amdgcn_mfma_f32_16x16x32_bf16(a1, b0, acc10, 0,0,0);
    acc11 = __builtin_amdgcn_mfma_f32_16x16x32_bf16(a1, b1, acc11, 0,0,0);
    __syncthreads();
  }
  if(docs) bv[bn+tid] -= LRATE*csum;
  int rb = lane>>4;
  #pragma unroll
  for(int ar=0;ar<2;ar++){
    #pragma unroll
    for(int bc=0;bc<2;bc++){
      f32x4 av = (ar==0) ? (bc==0?acc00:acc01) : (bc==0?acc10:acc11);
      #pragma unroll
      for(int i=0;i<4;i++){
        int lm = wr*32 + ar*16 + rb*4 + i;
        int ln = wc*32 + bc*16 + r16;
        size_t oi = (size_t)(bm+lm)*N + bn+ln;
        float wv = Wf[oi] - LRATE*av[i];
        Wf[oi] = wv;
        unsigned short ub = f2b(wv);
        Wb[oi] = ub;
        Tsm[ln*72 + lm] = (short)ub;
      }
    }
  }
  __syncthreads();
  #pragma unroll
  for(int q=0;q<2;q++){
    int id = tid*2+q;
    int ln = id>>3, ch = id&7;
    short8 vv = *(const short8*)(Tsm + ln*72 + ch*8);
    *(short8*)(Wt + (size_t)(bn+ln)*M + bm + ch*8) = vv;
  }
}

__global__ __launch_bounds__(256) void k_sgd_all(
    const unsigned short* __restrict__ z1gs, const unsigned short* __restrict__ dh2bB,
    const unsigned short* __restrict__ dz1bs, const float* __restrict__ h1s,
    const float* __restrict__ stats, int c,
    float* W1c, unsigned short* W1b, unsigned short* W1t, float* B1c,
    float* W2c, unsigned short* W2b, unsigned short* W2t, float* B2c,
    const float* __restrict__ ln2_g, const float* __restrict__ ln2_b)
{
  __shared__ __align__(16) short Asm[64*40], Bsm[64*40], Tsm[64*72];
  int gid = blockIdx.x;
  int i = gid>>9, r = gid&511;
  if(r<256){
    int bn=(r&7)*64, bm=(r>>3)*64;
    sgd_body<0>(z1gs+(size_t)i*524288, nullptr,nullptr,nullptr,nullptr,nullptr,
        dh2bB+(size_t)i*131072,
        W2c+(size_t)i*1048576, W2b+(size_t)i*1048576, W2t+(size_t)i*1048576, B2c+i*512,
        2048, 512, bm, bn, Asm,Bsm,Tsm);
  } else {
    int r2=r-256;
    int bn=(r2&31)*64, bm=(r2>>5)*64;
    const float* S1 = stats + ((size_t)(c*9+5+i)*2)*256;
    sgd_body<1>(nullptr, h1s+(size_t)i*131072, S1, S1+256, ln2_g+i*512, ln2_b+i*512,
        dz1bs+(size_t)i*524288,
        W1c+(size_t)i*1048576, W1b+(size_t)i*1048576, W1t+(size_t)i*1048576, B1c+i*2048,
        512, 2048, bm, bn, Asm,Bsm,Tsm);
  }
}

// ============ transpose-convert ============
__global__ __launch_bounds__(256) void k_cvt_t(const float* __restrict__ src,
    unsigned short* __restrict__ dstT, unsigned short* __restrict__ dstO, float* __restrict__ dstF,
    int R, int C)
{
  __shared__ __align__(16) short T[64*72];
  size_t zoff = (size_t)blockIdx.z * R * C;
  int c0 = blockIdx.x*64, r0 = blockIdx.y*64;
  int tid = threadIdx.x;
  #pragma unroll
  for(int q=0;q<16;q++){
    int e = tid + q*256;
    int r = e>>6, cc = e&63;
    float v = src[zoff + (size_t)(r0+r)*C + c0+cc];
    unsigned short bvu = f2b(v);
    T[cc*72 + r] = (short)bvu;
    if(dstO) dstO[zoff + (size_t)(r0+r)*C + c0+cc] = bvu;
    if(dstF) dstF[zoff + (size_t)(r0+r)*C + c0+cc] = v;
  }
  __syncthreads();
  #pragma unroll
  for(int q=0;q<2;q++){
    int id = tid*2+q;
    int cc = id>>3, ch = id&7;
    short8 vv = *(const short8*)(T + cc*72 + ch*8);
    *(short8*)(dstT + zoff + (size_t)(c0+cc)*R + r0 + ch*8) = vv;
  }
}

// ============ setup ============
__global__ __launch_bounds__(256) void k_setup(float* stats, float* B1c, const float* b1,
    float* B2c, const float* b2)
{
  int i = blockIdx.x*256 + threadIdx.x;
  if(i < 18432) stats[i] = 0.f;
  if(i < 8192)  B1c[i] = b1[i];
  if(i < 2048)  B2c[i] = b2[i];
}

// ============ embed + pos (+ LN stats); all 4 chunks in one launch ============
__global__ __launch_bounds__(256) void k_embed(const int* __restrict__ x, const float* __restrict__ emb,
    const float* __restrict__ pos, float* __restrict__ hinAll, float* __restrict__ stats)
{
  int n = blockIdx.x, chunk = blockIdx.y, tid = threadIdx.x;
  int b = n>>6, t = n&63;
  int tok = x[b*257 + chunk*64 + t];
  float* h = hinAll + (size_t)chunk*655360;
  size_t b0 = (size_t)n*512 + tid;
  float v0 = emb[(size_t)tok*512 + tid]       + pos[t*512 + tid];
  float v1 = emb[(size_t)tok*512 + tid + 256] + pos[t*512 + tid + 256];
  h[b0] = v0; h[b0+256] = v1;
  __shared__ float r1[256], r2[256];
  r1[tid] = v0+v1; r2[tid] = v0*v0+v1*v1;
  __syncthreads();
  for(int o=128;o;o>>=1){ if(tid<o){ r1[tid]+=r1[tid+o]; r2[tid]+=r2[tid+o]; } __syncthreads(); }
  if(tid==0){
    float* S1 = stats + ((size_t)(chunk*9)*2)*256;
    S1[n]=r1[0]; S1[256+n]=r2[0];
  }
}

// ============ LayerNorm bwd (wave-shuffle reductions; nz>0 sums split-K parts) ============
__global__ __launch_bounds__(256) void k_ln_bwd(const float* __restrict__ dy, const float* __restrict__ dp, int nz,
    const float* __restrict__ x, const float* __restrict__ g,
    const float* __restrict__ S1v, const float* __restrict__ S2v,
    const float* __restrict__ addin, float* __restrict__ dx, unsigned short* __restrict__ dxb)
{
  int n = blockIdx.x, tid = threadIdx.x;
  int lane = tid&63, w4 = tid>>6;
  float s1 = S1v[n], s2 = S2v[n];
  float m = s1*(1.f/512.f);
  float r = rsqrtf(s2*(1.f/512.f) - m*m + 1e-5f);
  size_t b0 = (size_t)n*512 + tid;
  float dy0, dy1;
  if(nz){
    dy0=0.f; dy1=0.f;
    for(int z=0;z<nz;z++){ dy0 += dp[(size_t)z*131072 + b0]; dy1 += dp[(size_t)z*131072 + b0 + 256]; }
  } else { dy0 = dy[b0]; dy1 = dy[b0+256]; }
  float x0 = x[b0], x1 = x[b0+256];
  float xh0 = (x0-m)*r, xh1 = (x1-m)*r;
  float gh0 = dy0*g[tid], gh1 = dy1*g[tid+256];
  float a1 = gh0+gh1, a2 = gh0*xh0 + gh1*xh1;
  #pragma unroll
  for(int off=32;off;off>>=1){ a1 += __shfl_xor(a1,off); a2 += __shfl_xor(a2,off); }
  __shared__ float rw[8];
  if(lane==0){ rw[w4]=a1; rw[4+w4]=a2; }
  __syncthreads();
  float mg  = (rw[0]+rw[1]+rw[2]+rw[3])*(1.f/512.f);
  float mgx = (rw[4]+rw[5]+rw[6]+rw[7])*(1.f/512.f);
  float d0 = (gh0 - mg - xh0*mgx)*r;
  float d1 = (gh1 - mg - xh1*mgx)*r;
  if(addin){ d0 += addin[b0]; d1 += addin[b0+256]; }
  dx[b0] = d0; dx[b0+256] = d1;
  dxb[b0] = f2b(d0); dxb[b0+256] = f2b(d1);
}

// ============ fused qkv GEMM (LN1 on-the-fly) + attention forward — 512 threads ============
__global__ __launch_bounds__(512) void k_qkv_attn(
    const float* __restrict__ h0, const float* __restrict__ S1, const float* __restrict__ S2,
    const float* __restrict__ lng, const float* __restrict__ lnb,
    const unsigned short* __restrict__ wT, const float* __restrict__ bias,
    unsigned short* __restrict__ qkB, unsigned short* __restrict__ obuf, unsigned short* __restrict__ ap)
{
  __shared__ __align__(16) short Afull[32768];
  __shared__ __align__(16) short Bsl[3*12288];
  short* Qs  = Bsl;
  short* Ks2 = Bsl + 4096;
  short* Vt  = Bsl + 8192;
  short* Pb  = Afull;
  float* Sf  = (float*)(Afull + 8192);
  int hh=blockIdx.x, bb=blockIdx.y;
  int tid=threadIdx.x, lane=tid&63, w=tid>>6;
  int r16=lane&15, kg=lane>>4, rb=lane>>4;

  {
    int arow=tid>>3, as8=tid&7, agc=as8^(arow&7);
    float mm,rr;
    { float a=S1[bb*64+arow], b2=S2[bb*64+arow]; mm=a*(1.f/512.f); rr=rsqrtf(b2*(1.f/512.f)-mm*mm+1e-5f); }
    for(int s=0;s<8;s++){
      const float* src = h0 + (size_t)(bb*64+arow)*512 + s*64 + agc*8;
      float4 v0=*(const float4*)src, v1=*(const float4*)(src+4);
      const float* gp=lng+s*64+agc*8; const float* bp=lnb+s*64+agc*8;
      float4 g0=*(const float4*)gp, g1=*(const float4*)(gp+4);
      float4 c0=*(const float4*)bp, c1=*(const float4*)(bp+4);
      short8 o;
      o[0]=(short)f2b((v0.x-mm)*rr*g0.x+c0.x);
      o[1]=(short)f2b((v0.y-mm)*rr*g0.y+c0.y);
      o[2]=(short)f2b((v0.z-mm)*rr*g0.z+c0.z);
      o[3]=(short)f2b((v0.w-mm)*rr*g0.w+c0.w);
      o[4]=(short)f2b((v1.x-mm)*rr*g1.x+c1.x);
      o[5]=(short)f2b((v1.y-mm)*rr*g1.y+c1.y);
      o[6]=(short)f2b((v1.z-mm)*rr*g1.z+c1.z);
      o[7]=(short)f2b((v1.w-mm)*rr*g1.w+c1.w);
      *(short8*)((char*)(Afull) + s*8192 + tid*16) = o;
    }
  }
  __syncthreads();

  auto STB=[&](int t,int slot){
    #pragma unroll
    for(int q=0;q<3;q++){
      int cid=q*512+tid, brow=cid>>3, s8=cid&7, gc=s8^(brow&7);
      int p=brow>>6, cin=brow&63;
      gll16(wT + (size_t)(p*512+hh*64+cin)*512 + t*64 + gc*8, (char*)Bsl + slot*24576 + cid*16);
    }
  };
  STB(0,0); STB(1,1);
  int wr=w>>2, wc=w&3;
  f32x4 acc[2][3]={};
  for(int t=0;t<8;t++){
    int tt=(t+2<8)? t+2 : 7;
    STB(tt,(t+2)%3);
    asm volatile("s_waitcnt vmcnt(6)" ::: "memory");
    __builtin_amdgcn_sched_barrier(0);
    __builtin_amdgcn_s_barrier();
    __builtin_amdgcn_sched_barrier(0);
    const char* Ab=(const char*)Afull + t*8192;
    const char* Bb=(const char*)Bsl + (t%3)*24576;
    #pragma unroll
    for(int h=0;h<2;h++){
      bf16x8 af[2], bfr[3];
      #pragma unroll
      for(int fa=0;fa<2;fa++){
        int rowa=wr*32+fa*16+r16, ca=(h*4+kg)^(rowa&7);
        af[fa]=__builtin_bit_cast(bf16x8, *(const short8*)(Ab + rowa*128 + ca*16));
      }
      #pragma unroll
      for(int fb=0;fb<3;fb++){
        int rowb=wc*48+fb*16+r16, cb=(h*4+kg)^(rowb&7);
        bfr[fb]=__builtin_bit_cast(bf16x8, *(const short8*)(Bb + rowb*128 + cb*16));
      }
      #pragma unroll
      for(int fa=0;fa<2;fa++)
        #pragma unroll
        for(int fb=0;fb<3;fb++)
          acc[fa][fb]=__builtin_amdgcn_mfma_f32_16x16x32_bf16(af[fa],bfr[fb],acc[fa][fb],0,0,0);
    }
    asm volatile("s_waitcnt lgkmcnt(0)" ::: "memory");
    __builtin_amdgcn_sched_barrier(0);
    __builtin_amdgcn_s_barrier();
    __builtin_amdgcn_sched_barrier(0);
  }
  asm volatile("s_waitcnt vmcnt(0)" ::: "memory");
  __syncthreads();

  #pragma unroll
  for(int fa=0;fa<2;fa++)
    #pragma unroll
    for(int fb=0;fb<3;fb++)
      #pragma unroll
      for(int i=0;i<4;i++){
        int row=wr*32+fa*16+rb*4+i;
        int band=wc*3+fb;
        int p=band>>2, cin=(band&3)*16+r16;
        float v = acc[fa][fb][i] + bias[p*512 + hh*64 + cin];
        unsigned short bv16 = f2b(v);
        qkB[(size_t)(bb*64+row)*1536 + p*512 + hh*64 + cin] = bv16;
        if(p==0)      tr_write(Qs,  row, cin, bv16);
        else if(p==1) tr_write(Ks2, row, cin, bv16);
        else          tr_write(Vt,  cin, row, bv16);
      }
  __syncthreads();

  int wr2=w>>2, wc2=w&3;
  f32x4 sa[2]={};
  #pragma unroll
  for(int h=0;h<2;h++){
    bf16x8 bfr = frag_read(Ks2, wc2*16+r16, h, kg);
    #pragma unroll
    for(int fa=0;fa<2;fa++){
      bf16x8 af = frag_read(Qs, wr2*32+fa*16+r16, h, kg);
      sa[fa]=__builtin_amdgcn_mfma_f32_16x16x32_bf16(af,bfr,sa[fa],0,0,0);
    }
  }
  #pragma unroll
  for(int fa=0;fa<2;fa++)
    #pragma unroll
    for(int i=0;i<4;i++){
      int row=wr2*32+fa*16+rb*4+i, col=wc2*16+r16;
      Sf[row*68+col] = (col<=row) ? sa[fa][i]*0.125f : -1e9f;
    }
  __syncthreads();

  {
    int srow=tid>>3, seg8=tid&7;
    float vals[8]; float mx=-3.4e38f;
    #pragma unroll
    for(int k2=0;k2<8;k2++){ vals[k2]=Sf[srow*68+seg8*8+k2]; mx=fmaxf(mx,vals[k2]); }
    mx=fmaxf(mx,__shfl_xor(mx,1)); mx=fmaxf(mx,__shfl_xor(mx,2)); mx=fmaxf(mx,__shfl_xor(mx,4));
    float sm=0;
    #pragma unroll
    for(int k2=0;k2<8;k2++){ vals[k2]=expf(vals[k2]-mx); sm+=vals[k2]; }
    sm+=__shfl_xor(sm,1); sm+=__shfl_xor(sm,2); sm+=__shfl_xor(sm,4);
    float inv=1.f/sm;
    short8 p0;
    #pragma unroll
    for(int k2=0;k2<8;k2++) p0[k2]=(short)f2b(vals[k2]*inv);
    __syncthreads();
    *(short8*)((char*)Pb + srow*128 + (((seg8)^(srow&7))<<4)) = p0;
    *(short8*)(ap + ((size_t)(bb*8+hh)*64 + srow)*64 + seg8*8) = p0;
  }
  __syncthreads();

  f32x4 oa[2]={};
  #pragma unroll
  for(int h=0;h<2;h++){
    bf16x8 bfr = frag_read(Vt, wc2*16+r16, h, kg);
    #pragma unroll
    for(int fa=0;fa<2;fa++){
      bf16x8 af = frag_read(Pb, wr2*32+fa*16+r16, h, kg);
      oa[fa]=__builtin_amdgcn_mfma_f32_16x16x32_bf16(af,bfr,oa[fa],0,0,0);
    }
  }
  #pragma unroll
  for(int fa=0;fa<2;fa++)
    #pragma unroll
    for(int i=0;i<4;i++){
      int row=wr2*32+fa*16+rb*4+i, col=wc2*16+r16;
      obuf[(size_t)(bb*64+row)*512 + hh*64 + col] = f2b(oa[fa][i]);
    }
}

// ============ fused do-GEMM + attention backward — 512 threads, group-parallel ============
__global__ __launch_bounds__(512) void k_do_attn(
    const unsigned short* __restrict__ dhBb, const unsigned short* __restrict__ projwB,
    const unsigned short* __restrict__ qkvB, const unsigned short* __restrict__ ap,
    unsigned short* __restrict__ dqkv)
{
  __shared__ __align__(16) short Asl[4*4096];
  __shared__ __align__(16) short Bsl2[4*4096];
  __shared__ __align__(16) short dOs[4096], Vs[4096], Kt[4096], Qt[4096], dOt[4096], Pt[4096], dsN[4096], dsT[4096];
  __shared__ float rsum[64][2];
  float* Pacc = (float*)Asl;
  int hh=blockIdx.x, bb=blockIdx.y;
  int tid=threadIdx.x, lane=tid&63, w=tid>>6;
  int wg=w>>2, wl=w&3;
  int wr=wl>>1, wc=wl&1, r16=lane&15, kg=lane>>4, rb=lane>>4;
  const unsigned short* qbase = qkvB + (size_t)bb*64*1536 + hh*64;
  const unsigned short* abase = ap + (size_t)(bb*8+hh)*64*64;

  {
    int row=tid>>3, gc=(tid&7)^(row&7);
    gll16(qbase + 1024 + (size_t)row*1536 + gc*8, (char*)Vs + tid*16);
  }
  {
    int row=tid>>3, c8=tid&7;
    short8 kreg=*(const short8*)(qbase+512+(size_t)row*1536+c8*8);
    short8 qreg=*(const short8*)(qbase+(size_t)row*1536+c8*8);
    short8 preg=*(const short8*)(abase+(size_t)row*64+c8*8);
    #pragma unroll
    for(int j=0;j<8;j++){
      int col=c8*8+j;
      tr_write(Kt, col, row, (unsigned short)kreg[j]);
      tr_write(Qt, col, row, (unsigned short)qreg[j]);
      tr_write(Pt, col, row, (unsigned short)preg[j]);
    }
  }

  const unsigned short* Bg = projwB + (size_t)(hh*64)*512;
  auto STAGE=[&](int t,int buf){
    int k0=(wg*4+t)*64;
    #pragma unroll
    for(int q=0;q<2;q++){
      int id=wl*128+q*64+lane, row=id>>3, gc=(id&7)^(row&7);
      gll16(dhBb + (size_t)(bb*64+row)*512 + k0 + gc*8, (char*)Asl + (wg*2+buf)*8192 + id*16);
      gll16(Bg + (size_t)row*512 + k0 + gc*8, (char*)Bsl2 + (wg*2+buf)*8192 + id*16);
    }
  };
  STAGE(0,0);
  f32x4 acc[2][2]={};
  for(int t=0;t<4;t++){
    int buf=t&1;
    STAGE(t+1<4?t+1:t, buf^1);
    asm volatile("s_waitcnt vmcnt(4)" ::: "memory");
    __builtin_amdgcn_sched_barrier(0);
    __builtin_amdgcn_s_barrier();
    __builtin_amdgcn_sched_barrier(0);
    const char* Ab=(const char*)Asl + (wg*2+buf)*8192;
    const char* Bb=(const char*)Bsl2 + (wg*2+buf)*8192;
    #pragma unroll
    for(int h=0;h<2;h++){
      bf16x8 af[2], bfr[2];
      #pragma unroll
      for(int f=0;f<2;f++){
        int rowa=wr*32+f*16+r16, ca=(h*4+kg)^(rowa&7);
        af[f]=__builtin_bit_cast(bf16x8, *(const short8*)(Ab + rowa*128 + ca*16));
        int rowb=wc*32+f*16+r16, cb=(h*4+kg)^(rowb&7);
        bfr[f]=__builtin_bit_cast(bf16x8, *(const short8*)(Bb + rowb*128 + cb*16));
      }
      #pragma unroll
      for(int fa=0;fa<2;fa++)
        #pragma unroll
        for(int fb=0;fb<2;fb++)
          acc[fa][fb]=__builtin_amdgcn_mfma_f32_16x16x32_bf16(af[fa],bfr[fb],acc[fa][fb],0,0,0);
    }
    asm volatile("s_waitcnt lgkmcnt(0)" ::: "memory");
    __builtin_amdgcn_sched_barrier(0);
    __builtin_amdgcn_s_barrier();
    __builtin_amdgcn_sched_barrier(0);
  }
  asm volatile("s_waitcnt vmcnt(0)" ::: "memory");
  __syncthreads();

  if(wg==1){
    #pragma unroll
    for(int fa=0;fa<2;fa++)
      #pragma unroll
      for(int fb=0;fb<2;fb++)
        #pragma unroll
        for(int i=0;i<4;i++){
          int row=wr*32+fa*16+rb*4+i, col=wc*32+fb*16+r16;
          Pacc[row*64+col]=acc[fa][fb][i];
        }
  }
  __syncthreads();
  if(wg==0){
    #pragma unroll
    for(int fa=0;fa<2;fa++)
      #pragma unroll
      for(int fb=0;fb<2;fb++)
        #pragma unroll
        for(int i=0;i<4;i++){
          int row=wr*32+fa*16+rb*4+i, col=wc*32+fb*16+r16;
          unsigned short db = f2b(acc[fa][fb][i] + Pacc[row*64+col]);
          tr_write(dOs, row, col, db);
          tr_write(dOt, col, row, db);
        }
  }
  __syncthreads();

  f32x4 da[2][2]={};
  float pv[2][2][4];
  if(wg==0){
    #pragma unroll
    for(int h=0;h<2;h++){
      bf16x8 af[2], bfr[2];
      #pragma unroll
      for(int f=0;f<2;f++){ af[f]=frag_read(dOs, wr*32+f*16+r16, h, kg); bfr[f]=frag_read(Vs, wc*32+f*16+r16, h, kg); }
      #pragma unroll
      for(int fa=0;fa<2;fa++)
        #pragma unroll
        for(int fb=0;fb<2;fb++)
          da[fa][fb]=__builtin_amdgcn_mfma_f32_16x16x32_bf16(af[fa],bfr[fb],da[fa][fb],0,0,0);
    }
    float part[2][4]={};
    #pragma unroll
    for(int fa=0;fa<2;fa++)
      #pragma unroll
      for(int i=0;i<4;i++){
        #pragma unroll
        for(int fb=0;fb<2;fb++){
          int row=wr*32+fa*16+rb*4+i, col=wc*32+fb*16+r16;
          float p = b2f(*(const unsigned short*)((const char*)Pt + col*128 + (((row>>3)^(col&7))<<4) + (row&7)*2));
          pv[fa][fb][i]=p;
          part[fa][i] += p*da[fa][fb][i];
        }
        float s=part[fa][i];
        #pragma unroll
        for(int msk=1;msk<16;msk<<=1) s += __shfl_xor(s,msk);
        if(r16==0) rsum[wr*32+fa*16+rb*4+i][wc]=s;
      }
  } else {
    f32x4 dvv[2][2]={};
    #pragma unroll
    for(int h=0;h<2;h++){
      bf16x8 af[2], bfr[2];
      #pragma unroll
      for(int f=0;f<2;f++){ af[f]=frag_read(Pt, wr*32+f*16+r16, h, kg); bfr[f]=frag_read(dOt, wc*32+f*16+r16, h, kg); }
      #pragma unroll
      for(int fa=0;fa<2;fa++)
        #pragma unroll
        for(int fb=0;fb<2;fb++)
          dvv[fa][fb]=__builtin_amdgcn_mfma_f32_16x16x32_bf16(af[fa],bfr[fb],dvv[fa][fb],0,0,0);
    }
    #pragma unroll
    for(int fa=0;fa<2;fa++)
      #pragma unroll
      for(int fb=0;fb<2;fb++)
        #pragma unroll
        for(int i=0;i<4;i++){
          int row=wr*32+fa*16+rb*4+i, col=wc*32+fb*16+r16;
          dqkv[(size_t)(bb*64+row)*1536 + hh*64 + 1024 + col] = f2b(dvv[fa][fb][i]);
        }
  }
  __syncthreads();

  if(wg==0){
    #pragma unroll
    for(int fa=0;fa<2;fa++)
      #pragma unroll
      for(int fb=0;fb<2;fb++)
        #pragma unroll
        for(int i=0;i<4;i++){
          int row=wr*32+fa*16+rb*4+i, col=wc*32+fb*16+r16;
          float rt = rsum[row][0]+rsum[row][1];
          float ds = pv[fa][fb][i]*(da[fa][fb][i]-rt)*0.125f;
          unsigned short db = f2b(ds);
          tr_write(dsN, row, col, db);
          tr_write(dsT, col, row, db);
        }
  }
  __syncthreads();

  {
    const short* Am = wg ? dsT : dsN;
    const short* Bm = wg ? Qt  : Kt;
    int ofs = wg ? 512 : 0;
    f32x4 a2[2][2]={};
    #pragma unroll
    for(int h=0;h<2;h++){
      bf16x8 af[2], bfr[2];
      #pragma unroll
      for(int f=0;f<2;f++){ af[f]=frag_read(Am, wr*32+f*16+r16, h, kg); bfr[f]=frag_read(Bm, wc*32+f*16+r16, h, kg); }
      #pragma unroll
      for(int fa=0;fa<2;fa++)
        #pragma unroll
        for(int fb=0;fb<2;fb++)
          a2[fa][fb]=__builtin_amdgcn_mfma_f32_16x16x32_bf16(af[fa],bfr[fb],a2[fa][fb],0,0,0);
    }
    #pragma unroll
    for(int fa=0;fa<2;fa++)
      #pragma unroll
      for(int fb=0;fb<2;fb++)
        #pragma unroll
        for(int i=0;i<4;i++){
          int row=wr*32+fa*16+rb*4+i, col=wc*32+fb*16+r16;
          dqkv[(size_t)(bb*64+row)*1536 + hh*64 + ofs + col] = f2b(a2[fa][fb][i]);
        }
  }
}

// ============ fused CE stats + dlogits -> bf16 (1024 threads, wave reductions) ============
__global__ __launch_bounds__(1024) void k_ce_dlog(const float* __restrict__ out, const int* __restrict__ x,
    unsigned short* __restrict__ dlog, int chunk)
{
  __shared__ unsigned short eb[32000];
  __shared__ float red[16];
  int n = blockIdx.x, tid = threadIdx.x;
  int lane = tid&63, w = tid>>6;
  int b = n>>6, t = n&63;
  int R = b*256 + chunk*64 + t;
  int tgt = x[b*257 + chunk*64 + t + 1];
  const float* row = out + (size_t)R*32000;

  float mx = -3.4e38f;
  for(int v=tid; v<32000; v+=1024){ float l=row[v]; mx=fmaxf(mx,l); eb[v]=f2b(l); }
  #pragma unroll
  for(int off=32;off;off>>=1) mx = fmaxf(mx, __shfl_xor(mx,off));
  if(lane==0) red[w]=mx;
  __syncthreads();
  float m = red[0];
  #pragma unroll
  for(int i=1;i<16;i++) m = fmaxf(m, red[i]);
  __syncthreads();

  float s=0;
  for(int v=tid; v<32000; v+=1024){ float e = expf(b2f(eb[v])-m); s+=e; eb[v]=f2b(e); }
  #pragma unroll
  for(int off=32;off;off>>=1) s += __shfl_xor(s,off);
  if(lane==0) red[w]=s;
  __syncthreads();
  float tot = 0.f;
  #pragma unroll
  for(int i=0;i<16;i++) tot += red[i];
  float iz = 1.f/tot * (1.f/256.f);

  unsigned short* dr = dlog + (size_t)n*32000;
  for(int v=tid; v<32000; v+=1024){
    float a = b2f(eb[v])*iz;
    if(v==tgt) a -= (1.f/256.f);
    dr[v] = f2b(a);
  }
}

extern "C" void kernel_launch(void* const* d_in, const int* in_sizes, int n_in,
                              void* d_out, int out_size, void* d_ws, size_t ws_size,
                              hipStream_t stream)
{
  const int*   x      = (const int*)d_in[0];
  const float* embed  = (const float*)d_in[1];
  const float* pos    = (const float*)d_in[2];
  const float* ln1_g  = (const float*)d_in[3];
  const float* ln1_b  = (const float*)d_in[4];
  const float* qkv_w  = (const float*)d_in[5];
  const float* qkv_b  = (const float*)d_in[6];
  const float* proj_w = (const float*)d_in[7];
  const float* proj_b = (const float*)d_in[8];
  const float* ln2_g  = (const float*)d_in[9];
  const float* ln2_b  = (const float*)d_in[10];
  const float* mlp_w1 = (const float*)d_in[11];
  const float* mlp_b1 = (const float*)d_in[12];
  const float* mlp_w2 = (const float*)d_in[13];
  const float* mlp_b2 = (const float*)d_in[14];
  const float* lnf_g  = (const float*)d_in[15];
  const float* lnf_b  = (const float*)d_in[16];
  const float* head_w = (const float*)d_in[17];
  const float* head_b = (const float*)d_in[18];
  float* out = (float*)d_out;

  char* base = (char*)d_ws;
  size_t off = 0;
  auto AB = [&](size_t bytes)->char*{ char* p = base + off; off += (bytes + 255) & ~(size_t)255; return p; };
  // fp32
  float* W1c  = (float*)AB(16777216);
  float* W2c  = (float*)AB(16777216);
  float* B1c  = (float*)AB(32768);
  float* B2c  = (float*)AB(8192);
  float* hins = (float*)AB(4*5*524288);     // per-chunk h checkpoints
  float* h1s  = (float*)AB(4*524288);
  float* dhA  = (float*)AB(524288);
  float* dhB  = (float*)AB(524288);
  float* dxn  = (float*)AB(524288);
  float* dpart= (float*)AB(32*524288);
  float* stats= (float*)AB(4*9*2*256*4);
  // bf16
  unsigned short* qkvwB = (unsigned short*)AB(6291456);
  unsigned short* qkvwT = (unsigned short*)AB(6291456);
  unsigned short* projwB= (unsigned short*)AB(2097152);
  unsigned short* projwT= (unsigned short*)AB(2097152);
  unsigned short* headwB= (unsigned short*)AB(32768000);
  unsigned short* headwT= (unsigned short*)AB(32768000);
  unsigned short* W1b   = (unsigned short*)AB(8388608);
  unsigned short* W1t   = (unsigned short*)AB(8388608);
  unsigned short* W2b   = (unsigned short*)AB(8388608);
  unsigned short* W2t   = (unsigned short*)AB(8388608);
  unsigned short* z1gs  = (unsigned short*)AB(4194304);
  unsigned short* z1bs  = (unsigned short*)AB(4194304);   // raw pre-gelu z1, bf16
  unsigned short* qkBs  = (unsigned short*)AB(4*786432);
  unsigned short* apBs  = (unsigned short*)AB(4*262144);
  unsigned short* obufB = (unsigned short*)AB(262144);
  unsigned short* dlogB = (unsigned short*)AB(16384000);
  unsigned short* dhbB  = (unsigned short*)AB(5*262144);
  unsigned short* dhBb  = (unsigned short*)AB(262144);
  unsigned short* dz1bs = (unsigned short*)AB(4*1048576);
  unsigned short* dqkvB = (unsigned short*)AB(786432);

  auto SS1 = [&](int c, int s)->float*{ return stats + ((size_t)(c*9+s)*2)*256; };
  auto SS2 = [&](int c, int s)->float*{ return stats + ((size_t)(c*9+s)*2)*256 + 256; };

  k_setup<<<72,256,0,stream>>>(stats, B1c, mlp_b1, B2c, mlp_b2);
  k_cvt_t<<<dim3(24,8,4),256,0,stream>>>(qkv_w, qkvwT, qkvwB, nullptr, 512, 1536);
  k_cvt_t<<<dim3(8,8,4),256,0,stream>>>(proj_w, projwT, projwB, nullptr, 512, 512);
  k_cvt_t<<<dim3(500,8,1),256,0,stream>>>(head_w, headwT, headwB, nullptr, 512, 32000);
  k_cvt_t<<<dim3(32,8,4),256,0,stream>>>(mlp_w1, W1t, W1b, W1c, 512, 2048);
  k_cvt_t<<<dim3(8,32,4),256,0,stream>>>(mlp_w2, W2t, W2b, W2c, 2048, 512);
  k_embed<<<dim3(256,4),256,0,stream>>>(x, embed, pos, hins, stats);

  for(int c=0;c<4;c++){
    float* hin = hins + (size_t)c*655360;
    // ---------------- forward ----------------
    for(int i=0;i<4;i++){
      float* h0 = hin + (size_t)i*131072;
      float* h2 = hin + (size_t)(i+1)*131072;
      float* h1 = h1s + (size_t)i*131072;
      unsigned short* z1g = z1gs + (size_t)i*524288;
      unsigned short* z1b = z1bs + (size_t)i*524288;
      unsigned short* qkB = qkBs + (size_t)i*393216;
      unsigned short* apB = apBs + (size_t)i*131072;
      k_qkv_attn<<<dim3(8,4),512,0,stream>>>(h0, SS1(c,i), SS2(c,i), ln1_g+i*512, ln1_b+i*512,
          qkvwT+(size_t)i*786432, qkv_b+i*1536, qkB, obufB, apB);
      k_nt32<0,1><<<dim3(16,8),256,0,stream>>>(obufB, nullptr, nullptr, nullptr, nullptr, nullptr,
          projwT+(size_t)i*262144, proj_b+i*512, h0, nullptr, nullptr,
          h1, nullptr, nullptr, SS1(c,5+i), SS2(c,5+i), 256,512,512, 8, 0);
      k_nt32<1,0><<<dim3(64,8),256,0,stream>>>(nullptr, h1, SS1(c,5+i), SS2(c,5+i), ln2_g+i*512, ln2_b+i*512,
          W1t+(size_t)i*1048576, B1c+i*2048, nullptr, nullptr, nullptr,
          nullptr, z1g, z1b, nullptr, nullptr, 256,2048,512, 8, 1);
      k_nt32<0,1><<<dim3(16,8),256,0,stream>>>(z1g, nullptr, nullptr, nullptr, nullptr, nullptr,
          W2t+(size_t)i*1048576, B2c+i*512, h1, nullptr, nullptr,
          h2, nullptr, nullptr, SS1(c,i+1), SS2(c,i+1), 256,512,2048, 32, 0);
    }
    k_nt<128,1,0><<<dim3(250,2),256,0,stream>>>(nullptr, hin+4*131072, SS1(c,4), SS2(c,4), lnf_g, lnf_b,
        headwT, head_b, nullptr, nullptr,
        out, nullptr, nullptr, nullptr, 256,32000,512, 8, 0, c);

    // ---------------- backward ----------------
    k_ce_dlog<<<256,1024,0,stream>>>(out, x, dlogB, c);
    k_nt<128,0,0><<<dim3(4,2,32),256,0,stream>>>(dlogB, nullptr, nullptr, nullptr, nullptr, nullptr,
        headwB, nullptr, nullptr, nullptr,
        dpart, nullptr, nullptr, nullptr, 256,512,32000, 16, 0, -1);
    k_ln_bwd<<<256,256,0,stream>>>(nullptr, dpart, 32, hin+4*131072, lnf_g, SS1(c,4), SS2(c,4),
        nullptr, dhA, dhbB + 3*131072);
    for(int i=3;i>=1;i--){
      float* h0 = hin + (size_t)i*131072;
      float* h1 = h1s + (size_t)i*131072;
      unsigned short* z1b = z1bs + (size_t)i*524288;
      unsigned short* qkB = qkBs + (size_t)i*393216;
      unsigned short* apB = apBs + (size_t)i*131072;
      k_nt32<0,0><<<dim3(64,8),256,0,stream>>>(dhbB + (size_t)i*131072, nullptr, nullptr, nullptr, nullptr, nullptr,
          W2b+(size_t)i*1048576, nullptr, nullptr, nullptr, z1b,
          nullptr, dz1bs + (size_t)i*524288, nullptr, nullptr, nullptr, 256,2048,512, 8, 0);
      k_nt32<0,0><<<dim3(16,8),256,0,stream>>>(dz1bs + (size_t)i*524288, nullptr, nullptr, nullptr, nullptr, nullptr,
          W1b+(size_t)i*1048576, nullptr, nullptr, nullptr, nullptr,
          dxn, nullptr, nullptr, nullptr, nullptr, 256,512,2048, 32, 0);
      k_ln_bwd<<<256,256,0,stream>>>(dxn, nullptr, 0, h1, ln2_g+i*512, SS1(c,5+i), SS2(c,5+i),
          dhA, dhB, dhBb);
      k_do_attn<<<dim3(8,4),512,0,stream>>>(dhBb, projwB+(size_t)i*262144, qkB, apB, dqkvB);
      k_nt32<0,0><<<dim3(16,8),256,0,stream>>>(dqkvB, nullptr, nullptr, nullptr, nullptr, nullptr,
          qkvwB+(size_t)i*786432, nullptr, nullptr, nullptr, nullptr,
          dxn, nullptr, nullptr, nullptr, nullptr, 256,512,1536, 24, 0);
      k_ln_bwd<<<256,256,0,stream>>>(dxn, nullptr, 0, h0, ln1_g+i*512, SS1(c,i), SS2(c,i),
          dhB, dhA, dhbB + (size_t)(i-1)*131072);
    }
    // i == 0: only dz1 is live (feeds W1/W2/b1/b2 updates).
    k_nt32<0,0><<<dim3(64,8),256,0,stream>>>(dhbB, nullptr, nullptr, nullptr, nullptr, nullptr,
        W2b, nullptr, nullptr, nullptr, z1bs,
        nullptr, dz1bs, nullptr, nullptr, nullptr, 256,2048,512, 8, 0);
    k_sgd_all<<<2048,256,0,stream>>>(z1gs, dhbB, dz1bs, h1s, stats, c,
        W1c, W1b, W1t, B1c, W2c, W2b, W2t, B2c, ln2_g, ln2_b);
  }
}